// Round 1
// baseline (336.825 us; speedup 1.0000x reference)
//
#include <hip/hip_runtime.h>
#include <hip/hip_bf16.h>

// MHSA: B=2, N=2048, C=1024, H=16, HS=64.
// Pipeline: convert(f32->bf16, permute w_qkv) -> QKV GEMM (bf16 MFMA)
//           -> flash attention -> out GEMM (+bias, f32 out).

typedef __attribute__((ext_vector_type(8))) short bfx8;
typedef __attribute__((ext_vector_type(4))) float f32x4;

#define B_ 2
#define N_ 2048
#define C_ 1024
#define H_ 16
#define HS_ 64
#define M_TOT 4096     // B*N
#define QKV_N 3072     // 3*C

__device__ __forceinline__ ushort f2bf(float f) {
  union { float f; unsigned u; } v; v.f = f;
  unsigned r = v.u + 0x7FFFu + ((v.u >> 16) & 1u);  // RNE
  return (ushort)(r >> 16);
}

__device__ __forceinline__ void gload_lds16(const ushort* g, ushort* l) {
  __builtin_amdgcn_global_load_lds(
      (const __attribute__((address_space(1))) unsigned int*)g,
      (__attribute__((address_space(3))) unsigned int*)l, 16, 0, 0);
}

// ---------------------------------------------------------------------------
// f32 -> bf16 conversion. w_qkv rows are permuted so the reference's stride-3
// interleave (qkv.reshape(b,n,c,3)) becomes contiguous [Q | K | V] panels:
// original out-feature j (= row of w_qkv) -> new row (j%3)*1024 + j/3.
// ---------------------------------------------------------------------------
__global__ void convert_kernel(const float4* __restrict__ x,
                               const float4* __restrict__ wqkv,
                               const float4* __restrict__ wout,
                               ushort* __restrict__ xb,
                               ushort* __restrict__ wqkvb,
                               ushort* __restrict__ woutb) {
  const int NX = (M_TOT * C_) / 4;     // 1048576 quads
  const int NW = (QKV_N * C_) / 4;     // 786432
  const int NO = (C_ * C_) / 4;        // 262144
  const int total = NX + NW + NO;
  const int stride = gridDim.x * blockDim.x;
  for (int i = blockIdx.x * blockDim.x + threadIdx.x; i < total; i += stride) {
    if (i < NX) {
      float4 v = x[i];
      ushort4 o; o.x = f2bf(v.x); o.y = f2bf(v.y); o.z = f2bf(v.z); o.w = f2bf(v.w);
      *(ushort4*)(xb + (size_t)i * 4) = o;
    } else if (i < NX + NW) {
      int q = i - NX;
      float4 v = wqkv[q];
      int e = q * 4;
      int j = e >> 10, col = e & 1023;
      int jp = ((j % 3) << 10) + (j / 3);
      ushort4 o; o.x = f2bf(v.x); o.y = f2bf(v.y); o.z = f2bf(v.z); o.w = f2bf(v.w);
      *(ushort4*)(wqkvb + ((size_t)jp << 10) + col) = o;
    } else {
      int q = i - NX - NW;
      float4 v = wout[q];
      ushort4 o; o.x = f2bf(v.x); o.y = f2bf(v.y); o.z = f2bf(v.z); o.w = f2bf(v.w);
      *(ushort4*)(woutb + (size_t)q * 4) = o;
    }
  }
}

// ---------------------------------------------------------------------------
// GEMM: C[M,N] = A[M,K] * B[N,K]^T  (both operands K-contiguous, "B^T" form).
// 128x128 tile, BK=64, 256 threads / 4 waves (2x2 quadrants of 64x64).
// Staging via global_load_lds width=16 into linear LDS (m97 structure).
// STORE_BF16=1 -> bf16 output; 0 -> f32 output + bias.
// ---------------------------------------------------------------------------
template<int STORE_BF16>
__global__ __launch_bounds__(256)
void gemm_bt(const ushort* __restrict__ A, const ushort* __restrict__ Bm,
             ushort* __restrict__ Cb, float* __restrict__ Cf,
             const float* __restrict__ bias, int M, int N, int K) {
  __shared__ ushort As[128 * 64];
  __shared__ ushort Bs[128 * 64];
  const int tid = threadIdx.x;
  const int wave = tid >> 6, lane = tid & 63;
  const int l16 = lane & 15, lq = lane >> 4;
  const int brow = blockIdx.y * 128, bcol = blockIdx.x * 128;
  const int wr = (wave >> 1) * 64, wc = (wave & 1) * 64;

  f32x4 acc[4][4];
#pragma unroll
  for (int m = 0; m < 4; ++m)
#pragma unroll
    for (int n = 0; n < 4; ++n) acc[m][n] = f32x4{0.f, 0.f, 0.f, 0.f};

  for (int k0 = 0; k0 < K; k0 += 64) {
    __syncthreads();
#pragma unroll
    for (int r = 0; r < 4; ++r) {
      int off = (r * 256 + tid) * 8;       // element offset in 128x64 tile
      gload_lds16(A + (size_t)(brow + (off >> 6)) * K + k0 + (off & 63), As + off);
    }
#pragma unroll
    for (int r = 0; r < 4; ++r) {
      int off = (r * 256 + tid) * 8;
      gload_lds16(Bm + (size_t)(bcol + (off >> 6)) * K + k0 + (off & 63), Bs + off);
    }
    asm volatile("s_waitcnt vmcnt(0)" ::: "memory");
    __syncthreads();
#pragma unroll
    for (int kk = 0; kk < 64; kk += 32) {
      bfx8 a[4], b[4];
#pragma unroll
      for (int m = 0; m < 4; ++m)
        a[m] = *(const bfx8*)(As + (wr + m * 16 + l16) * 64 + kk + lq * 8);
#pragma unroll
      for (int n = 0; n < 4; ++n)
        b[n] = *(const bfx8*)(Bs + (wc + n * 16 + l16) * 64 + kk + lq * 8);
#pragma unroll
      for (int m = 0; m < 4; ++m)
#pragma unroll
        for (int n = 0; n < 4; ++n)
          acc[m][n] = __builtin_amdgcn_mfma_f32_16x16x32_bf16(a[m], b[n], acc[m][n], 0, 0, 0);
    }
  }
#pragma unroll
  for (int m = 0; m < 4; ++m)
#pragma unroll
    for (int n = 0; n < 4; ++n)
#pragma unroll
      for (int r = 0; r < 4; ++r) {
        int grow = brow + wr + m * 16 + lq * 4 + r;
        int gcol = bcol + wc + n * 16 + l16;
        if (STORE_BF16) {
          Cb[(size_t)grow * N + gcol] = f2bf(acc[m][n][r]);
        } else {
          Cf[(size_t)grow * N + gcol] = acc[m][n][r] + bias[gcol];
        }
      }
}

// ---------------------------------------------------------------------------
// Flash attention. Grid: (N/64, B*H). 4 waves x 16 q-rows, KVBLK=64.
// qkv layout: row (b*N+n) stride 3072, cols [Q(h,d) | K(h,d) | V(h,d)].
// S tile via mfma(Q, K) (both frags row-major K-contiguous from global).
// Online softmax in the accumulator layout; P + transposed-V in LDS
// (XOR-swizzled, G4) feed the PV mfmas.
// ---------------------------------------------------------------------------
__global__ __launch_bounds__(256)
void attn_kernel(const ushort* __restrict__ qkv, ushort* __restrict__ outb) {
  __shared__ ushort Vt[64 * 64];       // Vt[d][j], swizzled
  __shared__ ushort P[4][16 * 64];     // per-wave P[i][j], swizzled
  const int tid = threadIdx.x, wave = tid >> 6, lane = tid & 63;
  const int l16 = lane & 15, lq = lane >> 4;
  const int bh = blockIdx.y, b = bh >> 4, h = bh & 15;
  const int q0 = blockIdx.x * 64;

  const size_t RS = QKV_N;
  const ushort* Qb = qkv + ((size_t)(b * N_ + q0)) * RS + h * HS_;
  const ushort* Kb = qkv + ((size_t)(b * N_)) * RS + C_ + h * HS_;
  const ushort* Vb = qkv + ((size_t)(b * N_)) * RS + 2 * C_ + h * HS_;

  bfx8 qf0, qf1;
  {
    const ushort* qrow = Qb + (size_t)(wave * 16 + l16) * RS + lq * 8;
    qf0 = *(const bfx8*)(qrow);
    qf1 = *(const bfx8*)(qrow + 32);
  }

  float m_r[4], l_r[4];
  f32x4 o[4];
#pragma unroll
  for (int r = 0; r < 4; ++r) { m_r[r] = -1e30f; l_r[r] = 0.f; }
#pragma unroll
  for (int dt = 0; dt < 4; ++dt) o[dt] = f32x4{0.f, 0.f, 0.f, 0.f};

  for (int kt = 0; kt < N_ / 64; ++kt) {
    const int j0 = kt * 64;
    __syncthreads();  // previous PV done reading Vt
    // ---- stage V tile transposed: Vt[d][j] ----
    {
      const int j = tid >> 2, d0 = (tid & 3) * 16;
      const ushort* vrow = Vb + (size_t)(j0 + j) * RS + d0;
      bfx8 v0 = *(const bfx8*)(vrow);
      bfx8 v1 = *(const bfx8*)(vrow + 8);
#pragma unroll
      for (int k2 = 0; k2 < 8; ++k2) {
        int row = d0 + k2;
        Vt[(row * 64 + j) ^ ((row & 7) << 3)] = (ushort)v0[k2];
      }
#pragma unroll
      for (int k2 = 0; k2 < 8; ++k2) {
        int row = d0 + 8 + k2;
        Vt[(row * 64 + j) ^ ((row & 7) << 3)] = (ushort)v1[k2];
      }
    }
    // ---- S = SCALE * Q K^T ----
    f32x4 s[4];
#pragma unroll
    for (int jt = 0; jt < 4; ++jt) {
      const ushort* krow = Kb + (size_t)(j0 + jt * 16 + l16) * RS + lq * 8;
      bfx8 kv0 = *(const bfx8*)(krow);
      bfx8 kv1 = *(const bfx8*)(krow + 32);
      f32x4 z = {0.f, 0.f, 0.f, 0.f};
      z = __builtin_amdgcn_mfma_f32_16x16x32_bf16(qf0, kv0, z, 0, 0, 0);
      z = __builtin_amdgcn_mfma_f32_16x16x32_bf16(qf1, kv1, z, 0, 0, 0);
      s[jt] = z;
    }
    // row max (rows live as (lq*4+r) across the 16 lanes of each group)
    float tmax[4];
#pragma unroll
    for (int r = 0; r < 4; ++r) tmax[r] = -1e30f;
#pragma unroll
    for (int jt = 0; jt < 4; ++jt)
#pragma unroll
      for (int r = 0; r < 4; ++r) {
        float v = s[jt][r] * 0.125f;
        s[jt][r] = v;
        tmax[r] = fmaxf(tmax[r], v);
      }
#pragma unroll
    for (int mset = 1; mset < 16; mset <<= 1)
#pragma unroll
      for (int r = 0; r < 4; ++r) tmax[r] = fmaxf(tmax[r], __shfl_xor(tmax[r], mset));
    float sc[4];
#pragma unroll
    for (int r = 0; r < 4; ++r) {
      float mn = fmaxf(m_r[r], tmax[r]);
      sc[r] = __expf(m_r[r] - mn);   // first tile: exp(-1e30 - mn) == 0
      m_r[r] = mn;
    }
    float tsum[4] = {0.f, 0.f, 0.f, 0.f};
#pragma unroll
    for (int jt = 0; jt < 4; ++jt)
#pragma unroll
      for (int r = 0; r < 4; ++r) {
        float p = __expf(s[jt][r] - m_r[r]);
        s[jt][r] = p;
        tsum[r] += p;
      }
#pragma unroll
    for (int mset = 1; mset < 16; mset <<= 1)
#pragma unroll
      for (int r = 0; r < 4; ++r) tsum[r] += __shfl_xor(tsum[r], mset);
#pragma unroll
    for (int r = 0; r < 4; ++r) l_r[r] = l_r[r] * sc[r] + tsum[r];
#pragma unroll
    for (int dt = 0; dt < 4; ++dt)
#pragma unroll
      for (int r = 0; r < 4; ++r) o[dt][r] *= sc[r];
    // ---- write P (bf16, swizzled) ----
    ushort* Pw = P[wave];
#pragma unroll
    for (int jt = 0; jt < 4; ++jt)
#pragma unroll
      for (int r = 0; r < 4; ++r) {
        int row = lq * 4 + r;
        Pw[(row * 64 + jt * 16 + l16) ^ ((row & 7) << 3)] = f2bf(s[jt][r]);
      }
    __syncthreads();  // Vt staged by all threads; P writes drained
    // ---- PV ----
    bfx8 pa0 = *(const bfx8*)(Pw + ((l16 * 64 + lq * 8) ^ ((l16 & 7) << 3)));
    bfx8 pa1 = *(const bfx8*)(Pw + ((l16 * 64 + 32 + lq * 8) ^ ((l16 & 7) << 3)));
#pragma unroll
    for (int dt = 0; dt < 4; ++dt) {
      int row = dt * 16 + l16;
      int base = row * 64;
      int sw = (row & 7) << 3;
      bfx8 vb0 = *(const bfx8*)(Vt + ((base + lq * 8) ^ sw));
      bfx8 vb1 = *(const bfx8*)(Vt + ((base + 32 + lq * 8) ^ sw));
      o[dt] = __builtin_amdgcn_mfma_f32_16x16x32_bf16(pa0, vb0, o[dt], 0, 0, 0);
      o[dt] = __builtin_amdgcn_mfma_f32_16x16x32_bf16(pa1, vb1, o[dt], 0, 0, 0);
    }
  }
  // epilogue: attn (b,n,h,d) as (4096, 1024) bf16
#pragma unroll
  for (int dt = 0; dt < 4; ++dt)
#pragma unroll
    for (int r = 0; r < 4; ++r) {
      int n = q0 + wave * 16 + lq * 4 + r;
      int col = h * HS_ + dt * 16 + l16;
      outb[(size_t)(b * N_ + n) * C_ + col] = f2bf(o[dt][r] / l_r[r]);
    }
}

// ---------------------------------------------------------------------------
extern "C" void kernel_launch(void* const* d_in, const int* in_sizes, int n_in,
                              void* d_out, int out_size, void* d_ws, size_t ws_size,
                              hipStream_t stream) {
  const float* x    = (const float*)d_in[0];
  const float* wqkv = (const float*)d_in[1];
  const float* wout = (const float*)d_in[2];
  const float* bout = (const float*)d_in[3];
  float* out = (float*)d_out;

  ushort* xb    = (ushort*)d_ws;                    //  4M elems
  ushort* wqkvb = xb + (size_t)M_TOT * C_;          //  3M
  ushort* woutb = wqkvb + (size_t)QKV_N * C_;       //  1M
  ushort* qkvb  = woutb + (size_t)C_ * C_;          // 12M
  ushort* attnb = qkvb + (size_t)M_TOT * QKV_N;     //  4M   (total 48 MB)

  convert_kernel<<<2048, 256, 0, stream>>>((const float4*)x, (const float4*)wqkv,
                                           (const float4*)wout, xb, wqkvb, woutb);
  dim3 g1(QKV_N / 128, M_TOT / 128);
  gemm_bt<1><<<g1, 256, 0, stream>>>(xb, wqkvb, qkvb, nullptr, nullptr, M_TOT, QKV_N, C_);
  dim3 g2(N_ / 64, B_ * H_);
  attn_kernel<<<g2, 256, 0, stream>>>(qkvb, attnb);
  dim3 g3(C_ / 128, M_TOT / 128);
  gemm_bt<0><<<g3, 256, 0, stream>>>(attnb, woutb, nullptr, out, bout, M_TOT, C_, C_);
}

// Round 2
// 266.105 us; speedup vs baseline: 1.2658x; 1.2658x over previous
//
#include <hip/hip_runtime.h>
#include <hip/hip_bf16.h>

// MHSA: B=2, N=2048, C=1024, H=16, HS=64.
// Pipeline: convert(f32->bf16, permute w_qkv) -> QKV GEMM (bf16 MFMA)
//           -> flash attention (dbuf LDS K/V, tr_b16 V reads) -> out GEMM.

typedef __attribute__((ext_vector_type(8))) short bfx8;
typedef __attribute__((ext_vector_type(4))) short bfx4;
typedef __attribute__((ext_vector_type(4))) float f32x4;

#define B_ 2
#define N_ 2048
#define C_ 1024
#define H_ 16
#define HS_ 64
#define M_TOT 4096     // B*N
#define QKV_N 3072     // 3*C

__device__ __forceinline__ ushort f2bf(float f) {
  union { float f; unsigned u; } v; v.f = f;
  unsigned r = v.u + 0x7FFFu + ((v.u >> 16) & 1u);  // RNE
  return (ushort)(r >> 16);
}

__device__ __forceinline__ void gload_lds16(const ushort* g, ushort* l) {
  __builtin_amdgcn_global_load_lds(
      (const __attribute__((address_space(1))) unsigned int*)g,
      (__attribute__((address_space(3))) unsigned int*)l, 16, 0, 0);
}

__device__ __forceinline__ uint32_t lds_addr(const ushort* p) {
  return (uint32_t)(size_t)(__attribute__((address_space(3))) const ushort*)p;
}

// ---------------------------------------------------------------------------
// f32 -> bf16 conversion. w_qkv rows permuted: j' = (j%3)*1024 + j/3 so the
// stride-3 q/k/v interleave becomes contiguous [Q | K | V] panels.
// ---------------------------------------------------------------------------
__global__ void convert_kernel(const float4* __restrict__ x,
                               const float4* __restrict__ wqkv,
                               const float4* __restrict__ wout,
                               ushort* __restrict__ xb,
                               ushort* __restrict__ wqkvb,
                               ushort* __restrict__ woutb) {
  const int NX = (M_TOT * C_) / 4;
  const int NW = (QKV_N * C_) / 4;
  const int NO = (C_ * C_) / 4;
  const int total = NX + NW + NO;
  const int stride = gridDim.x * blockDim.x;
  for (int i = blockIdx.x * blockDim.x + threadIdx.x; i < total; i += stride) {
    if (i < NX) {
      float4 v = x[i];
      ushort4 o; o.x = f2bf(v.x); o.y = f2bf(v.y); o.z = f2bf(v.z); o.w = f2bf(v.w);
      *(ushort4*)(xb + (size_t)i * 4) = o;
    } else if (i < NX + NW) {
      int q = i - NX;
      float4 v = wqkv[q];
      int e = q * 4;
      int j = e >> 10, col = e & 1023;
      int jp = ((j % 3) << 10) + (j / 3);
      ushort4 o; o.x = f2bf(v.x); o.y = f2bf(v.y); o.z = f2bf(v.z); o.w = f2bf(v.w);
      *(ushort4*)(wqkvb + ((size_t)jp << 10) + col) = o;
    } else {
      int q = i - NX - NW;
      float4 v = wout[q];
      ushort4 o; o.x = f2bf(v.x); o.y = f2bf(v.y); o.z = f2bf(v.z); o.w = f2bf(v.w);
      *(ushort4*)(woutb + (size_t)q * 4) = o;
    }
  }
}

// ---------------------------------------------------------------------------
// GEMM: C[M,N] = A[M,K] * B[N,K]^T, 128x128 tile, BK=64, 4 waves (m97-style).
// ---------------------------------------------------------------------------
template<int STORE_BF16>
__global__ __launch_bounds__(256)
void gemm_bt(const ushort* __restrict__ A, const ushort* __restrict__ Bm,
             ushort* __restrict__ Cb, float* __restrict__ Cf,
             const float* __restrict__ bias, int M, int N, int K) {
  __shared__ ushort As[128 * 64];
  __shared__ ushort Bs[128 * 64];
  const int tid = threadIdx.x;
  const int wave = tid >> 6, lane = tid & 63;
  const int l16 = lane & 15, lq = lane >> 4;
  const int brow = blockIdx.y * 128, bcol = blockIdx.x * 128;
  const int wr = (wave >> 1) * 64, wc = (wave & 1) * 64;

  f32x4 acc[4][4];
#pragma unroll
  for (int m = 0; m < 4; ++m)
#pragma unroll
    for (int n = 0; n < 4; ++n) acc[m][n] = f32x4{0.f, 0.f, 0.f, 0.f};

  for (int k0 = 0; k0 < K; k0 += 64) {
    __syncthreads();
#pragma unroll
    for (int r = 0; r < 4; ++r) {
      int off = (r * 256 + tid) * 8;
      gload_lds16(A + (size_t)(brow + (off >> 6)) * K + k0 + (off & 63), As + off);
    }
#pragma unroll
    for (int r = 0; r < 4; ++r) {
      int off = (r * 256 + tid) * 8;
      gload_lds16(Bm + (size_t)(bcol + (off >> 6)) * K + k0 + (off & 63), Bs + off);
    }
    asm volatile("s_waitcnt vmcnt(0)" ::: "memory");
    __syncthreads();
#pragma unroll
    for (int kk = 0; kk < 64; kk += 32) {
      bfx8 a[4], b[4];
#pragma unroll
      for (int m = 0; m < 4; ++m)
        a[m] = *(const bfx8*)(As + (wr + m * 16 + l16) * 64 + kk + lq * 8);
#pragma unroll
      for (int n = 0; n < 4; ++n)
        b[n] = *(const bfx8*)(Bs + (wc + n * 16 + l16) * 64 + kk + lq * 8);
#pragma unroll
      for (int m = 0; m < 4; ++m)
#pragma unroll
        for (int n = 0; n < 4; ++n)
          acc[m][n] = __builtin_amdgcn_mfma_f32_16x16x32_bf16(a[m], b[n], acc[m][n], 0, 0, 0);
    }
  }
#pragma unroll
  for (int m = 0; m < 4; ++m)
#pragma unroll
    for (int n = 0; n < 4; ++n)
#pragma unroll
      for (int r = 0; r < 4; ++r) {
        int grow = brow + wr + m * 16 + lq * 4 + r;
        int gcol = bcol + wc + n * 16 + l16;
        if (STORE_BF16) {
          Cb[(size_t)grow * N + gcol] = f2bf(acc[m][n][r]);
        } else {
          Cf[(size_t)grow * N + gcol] = acc[m][n][r] + bias[gcol];
        }
      }
}

// ---------------------------------------------------------------------------
// Flash attention. Grid (N/64, B*H), 4 waves x 16 q-rows, KVBLK=64.
// K LDS: [row][slot^(row&7)] (swizzled via pre-swizzled global source).
// V LDS: subtiled [jb][db][4][16] linear, consumed by ds_read_b64_tr_b16.
// Double-buffered; one __syncthreads per tile (drains gload_lds prefetch).
// ---------------------------------------------------------------------------
__global__ __launch_bounds__(256)
void attn_kernel(const ushort* __restrict__ qkv, ushort* __restrict__ outb) {
  __shared__ ushort Ks[2][64 * 64];
  __shared__ ushort Vs[2][64 * 64];
  __shared__ ushort Ps[4][16 * 64];
  const int tid = threadIdx.x, wave = tid >> 6, lane = tid & 63;
  const int l16 = lane & 15, lq = lane >> 4;
  const int bh = blockIdx.y, b = bh >> 4, h = bh & 15;
  const int q0 = blockIdx.x * 64;
  const size_t RS = QKV_N;
  const ushort* Qb = qkv + ((size_t)(b * N_ + q0)) * RS + h * HS_;
  const ushort* Kb = qkv + ((size_t)(b * N_)) * RS + C_ + h * HS_;
  const ushort* Vb = qkv + ((size_t)(b * N_)) * RS + 2 * C_ + h * HS_;

  // per-lane staging geometry
  const int kRow = lane >> 3;                               // row within 8-row slab
  const int kCol = (((lane & 7) ^ (lane >> 3)) << 3);       // pre-swizzled k-slot
  const int vJ = ((lane >> 5) << 2) + ((lane & 7) >> 1);    // j within 8-row slab
  const int vD = ((lane >> 3) & 3) * 16 + (lane & 1) * 8;   // d offset

  bfx8 qf0, qf1;
  {
    const ushort* qrow = Qb + (size_t)(wave * 16 + l16) * RS + lq * 8;
    qf0 = *(const bfx8*)(qrow);
    qf1 = *(const bfx8*)(qrow + 32);
  }

  float m_r[4], l_r[4];
  f32x4 o[4];
#pragma unroll
  for (int r = 0; r < 4; ++r) { m_r[r] = -1e30f; l_r[r] = 0.f; }
#pragma unroll
  for (int dt = 0; dt < 4; ++dt) o[dt] = f32x4{0.f, 0.f, 0.f, 0.f};

#define STAGE_TILE(KT, BUF)                                                     \
  {                                                                             \
    const ushort* kbase = Kb + (size_t)((KT) * 64) * RS;                        \
    const ushort* vbase = Vb + (size_t)((KT) * 64) * RS;                        \
    _Pragma("unroll")                                                           \
    for (int t = 0; t < 2; ++t) {                                               \
      int it = wave * 2 + t;                                                    \
      gload_lds16(kbase + (size_t)(it * 8 + kRow) * RS + kCol,                  \
                  &Ks[BUF][it * 512]);                                          \
      gload_lds16(vbase + (size_t)(it * 8 + vJ) * RS + vD,                      \
                  &Vs[BUF][it * 512]);                                          \
    }                                                                           \
  }

  STAGE_TILE(0, 0);
  __syncthreads();
  int cur = 0;

  for (int kt = 0; kt < N_ / 64; ++kt) {
    if (kt + 1 < N_ / 64) STAGE_TILE(kt + 1, cur ^ 1);

    // ---- S = SCALE * Q K^T (K from swizzled LDS) ----
    f32x4 s[4];
    const ushort* Kc = Ks[cur];
#pragma unroll
    for (int jt = 0; jt < 4; ++jt) {
      int row = jt * 16 + l16, swz = l16 & 7;
      const ushort* kr = Kc + row * 64;
      bfx8 kv0 = *(const bfx8*)(kr + ((lq ^ swz) << 3));
      bfx8 kv1 = *(const bfx8*)(kr + (((lq + 4) ^ swz) << 3));
      f32x4 z = {0.f, 0.f, 0.f, 0.f};
      z = __builtin_amdgcn_mfma_f32_16x16x32_bf16(qf0, kv0, z, 0, 0, 0);
      z = __builtin_amdgcn_mfma_f32_16x16x32_bf16(qf1, kv1, z, 0, 0, 0);
      s[jt] = z;
    }
    // ---- online softmax ----
    float tmax[4];
#pragma unroll
    for (int r = 0; r < 4; ++r) tmax[r] = -1e30f;
#pragma unroll
    for (int jt = 0; jt < 4; ++jt)
#pragma unroll
      for (int r = 0; r < 4; ++r) {
        float v = s[jt][r] * 0.125f;
        s[jt][r] = v;
        tmax[r] = fmaxf(tmax[r], v);
      }
#pragma unroll
    for (int mset = 1; mset < 16; mset <<= 1)
#pragma unroll
      for (int r = 0; r < 4; ++r) tmax[r] = fmaxf(tmax[r], __shfl_xor(tmax[r], mset));
    float sc[4];
#pragma unroll
    for (int r = 0; r < 4; ++r) {
      float mn = fmaxf(m_r[r], tmax[r]);
      sc[r] = __expf(m_r[r] - mn);
      m_r[r] = mn;
    }
    float tsum[4] = {0.f, 0.f, 0.f, 0.f};
#pragma unroll
    for (int jt = 0; jt < 4; ++jt)
#pragma unroll
      for (int r = 0; r < 4; ++r) {
        float p = __expf(s[jt][r] - m_r[r]);
        s[jt][r] = p;
        tsum[r] += p;
      }
#pragma unroll
    for (int mset = 1; mset < 16; mset <<= 1)
#pragma unroll
      for (int r = 0; r < 4; ++r) tsum[r] += __shfl_xor(tsum[r], mset);
#pragma unroll
    for (int r = 0; r < 4; ++r) l_r[r] = l_r[r] * sc[r] + tsum[r];
#pragma unroll
    for (int dt = 0; dt < 4; ++dt)
#pragma unroll
      for (int r = 0; r < 4; ++r) o[dt][r] *= sc[r];

    // ---- write P (bf16, key = ((row>>1)&7)<<3 so rows 4 apart differ) ----
    ushort* Pw = Ps[wave];
#pragma unroll
    for (int jt = 0; jt < 4; ++jt)
#pragma unroll
      for (int r = 0; r < 4; ++r) {
        int row = lq * 4 + r;
        Pw[(row * 64 + jt * 16 + l16) ^ (((row >> 1) & 7) << 3)] = f2bf(s[jt][r]);
      }
    // wave-private P: in-wave lgkm drain instead of a barrier
    asm volatile("s_waitcnt lgkmcnt(0)" ::: "memory");
    __builtin_amdgcn_sched_barrier(0);
    const int pkey = ((l16 >> 1) & 7) << 3;
    bfx8 pa0 = *(const bfx8*)(Pw + ((l16 * 64 + lq * 8) ^ pkey));
    bfx8 pa1 = *(const bfx8*)(Pw + ((l16 * 64 + 32 + lq * 8) ^ pkey));

    // ---- PV: V via hardware transpose reads ----
    uint32_t vbase = lds_addr(&Vs[cur][0]) + (uint32_t)(lq * 1024 + l16 * 8);
#pragma unroll
    for (int kk = 0; kk < 2; ++kk) {
      bfx4 t[8];
#pragma unroll
      for (int dt = 0; dt < 4; ++dt)
#pragma unroll
        for (int hf = 0; hf < 2; ++hf) {
          uint32_t a = vbase + (uint32_t)(kk * 4096 + hf * 512 + dt * 128);
          asm volatile("ds_read_b64_tr_b16 %0, %1" : "=v"(t[dt * 2 + hf]) : "v"(a));
        }
      asm volatile("s_waitcnt lgkmcnt(0)" ::: "memory");
      __builtin_amdgcn_sched_barrier(0);
      bfx8 pa = kk ? pa1 : pa0;
#pragma unroll
      for (int dt = 0; dt < 4; ++dt) {
        bfx8 vf = __builtin_shufflevector(t[dt * 2], t[dt * 2 + 1],
                                          0, 1, 2, 3, 4, 5, 6, 7);
        o[dt] = __builtin_amdgcn_mfma_f32_16x16x32_bf16(pa, vf, o[dt], 0, 0, 0);
      }
    }
    __syncthreads();   // drains prefetch vmcnt + all waves done with buf[cur]
    cur ^= 1;
  }
#undef STAGE_TILE

  // epilogue: attn (b,n,h,d) as (4096, 1024) bf16
#pragma unroll
  for (int dt = 0; dt < 4; ++dt)
#pragma unroll
    for (int r = 0; r < 4; ++r) {
      int n = q0 + wave * 16 + lq * 4 + r;
      int col = h * HS_ + dt * 16 + l16;
      outb[(size_t)(b * N_ + n) * C_ + col] = f2bf(o[dt][r] / l_r[r]);
    }
}

// ---------------------------------------------------------------------------
extern "C" void kernel_launch(void* const* d_in, const int* in_sizes, int n_in,
                              void* d_out, int out_size, void* d_ws, size_t ws_size,
                              hipStream_t stream) {
  const float* x    = (const float*)d_in[0];
  const float* wqkv = (const float*)d_in[1];
  const float* wout = (const float*)d_in[2];
  const float* bout = (const float*)d_in[3];
  float* out = (float*)d_out;

  ushort* xb    = (ushort*)d_ws;
  ushort* wqkvb = xb + (size_t)M_TOT * C_;
  ushort* woutb = wqkvb + (size_t)QKV_N * C_;
  ushort* qkvb  = woutb + (size_t)C_ * C_;
  ushort* attnb = qkvb + (size_t)M_TOT * QKV_N;

  convert_kernel<<<2048, 256, 0, stream>>>((const float4*)x, (const float4*)wqkv,
                                           (const float4*)wout, xb, wqkvb, woutb);
  dim3 g1(QKV_N / 128, M_TOT / 128);
  gemm_bt<1><<<g1, 256, 0, stream>>>(xb, wqkvb, qkvb, nullptr, nullptr, M_TOT, QKV_N, C_);
  dim3 g2(N_ / 64, B_ * H_);
  attn_kernel<<<g2, 256, 0, stream>>>(qkvb, attnb);
  dim3 g3(C_ / 128, M_TOT / 128);
  gemm_bt<0><<<g3, 256, 0, stream>>>(attnb, woutb, nullptr, out, bout, M_TOT, C_, C_);
}

// Round 3
// 222.746 us; speedup vs baseline: 1.5121x; 1.1947x over previous
//
#include <hip/hip_runtime.h>
#include <hip/hip_bf16.h>

// MHSA: B=2, N=2048, C=1024, H=16, HS=64.
// Pipeline: convert(f32->bf16, permute w_qkv) -> QKV GEMM (bf16 MFMA)
//           -> flash attention (swapped QK^T, lane-local softmax) -> out GEMM.

typedef __attribute__((ext_vector_type(8))) short bfx8;
typedef __attribute__((ext_vector_type(4))) short bfx4;
typedef __attribute__((ext_vector_type(4))) float f32x4;

#define B_ 2
#define N_ 2048
#define C_ 1024
#define H_ 16
#define HS_ 64
#define M_TOT 4096     // B*N
#define QKV_N 3072     // 3*C

__device__ __forceinline__ ushort f2bf(float f) {
  union { float f; unsigned u; } v; v.f = f;
  unsigned r = v.u + 0x7FFFu + ((v.u >> 16) & 1u);  // RNE
  return (ushort)(r >> 16);
}

__device__ __forceinline__ void gload_lds16(const ushort* g, ushort* l) {
  __builtin_amdgcn_global_load_lds(
      (const __attribute__((address_space(1))) unsigned int*)g,
      (__attribute__((address_space(3))) unsigned int*)l, 16, 0, 0);
}

__device__ __forceinline__ uint32_t lds_addr(const ushort* p) {
  return (uint32_t)(size_t)(__attribute__((address_space(3))) const ushort*)p;
}

// ---------------------------------------------------------------------------
// f32 -> bf16 conversion. w_qkv rows permuted: j' = (j%3)*1024 + j/3 so the
// stride-3 q/k/v interleave becomes contiguous [Q | K | V] panels.
// ---------------------------------------------------------------------------
__global__ void convert_kernel(const float4* __restrict__ x,
                               const float4* __restrict__ wqkv,
                               const float4* __restrict__ wout,
                               ushort* __restrict__ xb,
                               ushort* __restrict__ wqkvb,
                               ushort* __restrict__ woutb) {
  const int NX = (M_TOT * C_) / 4;
  const int NW = (QKV_N * C_) / 4;
  const int NO = (C_ * C_) / 4;
  const int total = NX + NW + NO;
  const int stride = gridDim.x * blockDim.x;
  for (int i = blockIdx.x * blockDim.x + threadIdx.x; i < total; i += stride) {
    if (i < NX) {
      float4 v = x[i];
      ushort4 o; o.x = f2bf(v.x); o.y = f2bf(v.y); o.z = f2bf(v.z); o.w = f2bf(v.w);
      *(ushort4*)(xb + (size_t)i * 4) = o;
    } else if (i < NX + NW) {
      int q = i - NX;
      float4 v = wqkv[q];
      int e = q * 4;
      int j = e >> 10, col = e & 1023;
      int jp = ((j % 3) << 10) + (j / 3);
      ushort4 o; o.x = f2bf(v.x); o.y = f2bf(v.y); o.z = f2bf(v.z); o.w = f2bf(v.w);
      *(ushort4*)(wqkvb + ((size_t)jp << 10) + col) = o;
    } else {
      int q = i - NX - NW;
      float4 v = wout[q];
      ushort4 o; o.x = f2bf(v.x); o.y = f2bf(v.y); o.z = f2bf(v.z); o.w = f2bf(v.w);
      *(ushort4*)(woutb + (size_t)q * 4) = o;
    }
  }
}

// ---------------------------------------------------------------------------
// GEMM: C[M,N] = A[M,K] * B[N,K]^T, 128x128 tile, BK=64, 4 waves (m97-style).
// ---------------------------------------------------------------------------
template<int STORE_BF16>
__global__ __launch_bounds__(256)
void gemm_bt(const ushort* __restrict__ A, const ushort* __restrict__ Bm,
             ushort* __restrict__ Cb, float* __restrict__ Cf,
             const float* __restrict__ bias, int M, int N, int K) {
  __shared__ ushort As[128 * 64];
  __shared__ ushort Bs[128 * 64];
  const int tid = threadIdx.x;
  const int wave = tid >> 6, lane = tid & 63;
  const int l16 = lane & 15, lq = lane >> 4;
  const int brow = blockIdx.y * 128, bcol = blockIdx.x * 128;
  const int wr = (wave >> 1) * 64, wc = (wave & 1) * 64;

  f32x4 acc[4][4];
#pragma unroll
  for (int m = 0; m < 4; ++m)
#pragma unroll
    for (int n = 0; n < 4; ++n) acc[m][n] = f32x4{0.f, 0.f, 0.f, 0.f};

  for (int k0 = 0; k0 < K; k0 += 64) {
    __syncthreads();
#pragma unroll
    for (int r = 0; r < 4; ++r) {
      int off = (r * 256 + tid) * 8;
      gload_lds16(A + (size_t)(brow + (off >> 6)) * K + k0 + (off & 63), As + off);
    }
#pragma unroll
    for (int r = 0; r < 4; ++r) {
      int off = (r * 256 + tid) * 8;
      gload_lds16(Bm + (size_t)(bcol + (off >> 6)) * K + k0 + (off & 63), Bs + off);
    }
    asm volatile("s_waitcnt vmcnt(0)" ::: "memory");
    __syncthreads();
#pragma unroll
    for (int kk = 0; kk < 64; kk += 32) {
      bfx8 a[4], b[4];
#pragma unroll
      for (int m = 0; m < 4; ++m)
        a[m] = *(const bfx8*)(As + (wr + m * 16 + l16) * 64 + kk + lq * 8);
#pragma unroll
      for (int n = 0; n < 4; ++n)
        b[n] = *(const bfx8*)(Bs + (wc + n * 16 + l16) * 64 + kk + lq * 8);
#pragma unroll
      for (int m = 0; m < 4; ++m)
#pragma unroll
        for (int n = 0; n < 4; ++n)
          acc[m][n] = __builtin_amdgcn_mfma_f32_16x16x32_bf16(a[m], b[n], acc[m][n], 0, 0, 0);
    }
  }
#pragma unroll
  for (int m = 0; m < 4; ++m)
#pragma unroll
    for (int n = 0; n < 4; ++n)
#pragma unroll
      for (int r = 0; r < 4; ++r) {
        int grow = brow + wr + m * 16 + lq * 4 + r;
        int gcol = bcol + wc + n * 16 + l16;
        if (STORE_BF16) {
          Cb[(size_t)grow * N + gcol] = f2bf(acc[m][n][r]);
        } else {
          Cf[(size_t)grow * N + gcol] = acc[m][n][r] + bias[gcol];
        }
      }
}

// ---------------------------------------------------------------------------
// Flash attention. Grid (N/64, B*H), 4 waves x 16 q-rows, KVBLK=64.
// S^T via mfma(K, Q): lane holds q=l16, j=jt*16+lq*4+r -> lane-local softmax
// (log2-domain exp, defer-max THR=8, per-lane partial l reduced at end).
// K LDS swizzled via pre-swizzled global source; V subtiled for tr_b16 reads.
// ---------------------------------------------------------------------------
__global__ __launch_bounds__(256)
void attn_kernel(const ushort* __restrict__ qkv, ushort* __restrict__ outb) {
  __shared__ ushort Ks[2][64 * 64];
  __shared__ ushort Vs[2][64 * 64];
  __shared__ ushort Ps[4][16 * 64];
  const int tid = threadIdx.x, wave = tid >> 6, lane = tid & 63;
  const int l16 = lane & 15, lq = lane >> 4;
  const int bh = blockIdx.y, b = bh >> 4, h = bh & 15;
  const int q0 = blockIdx.x * 64;
  const size_t RS = QKV_N;
  const ushort* Qb = qkv + ((size_t)(b * N_ + q0)) * RS + h * HS_;
  const ushort* Kb = qkv + ((size_t)(b * N_)) * RS + C_ + h * HS_;
  const ushort* Vb = qkv + ((size_t)(b * N_)) * RS + 2 * C_ + h * HS_;

  // per-lane staging geometry
  const int kRow = lane >> 3;                               // row within 8-row slab
  const int kCol = (((lane & 7) ^ (lane >> 3)) << 3);       // pre-swizzled k-slot
  const int vJ = ((lane >> 5) << 2) + ((lane & 7) >> 1);    // j within 8-row slab
  const int vD = ((lane >> 3) & 3) * 16 + (lane & 1) * 8;   // d offset

  bfx8 qf0, qf1;
  {
    const ushort* qrow = Qb + (size_t)(wave * 16 + l16) * RS + lq * 8;
    qf0 = *(const bfx8*)(qrow);
    qf1 = *(const bfx8*)(qrow + 32);
  }

  const float CL = 0.125f * 1.44269504f;   // SCALE * log2(e)
  float m2 = -1e30f, l_s = 0.f;            // per-lane stats for q = l16 (log2 dom)
  f32x4 o[4];
#pragma unroll
  for (int dt = 0; dt < 4; ++dt) o[dt] = f32x4{0.f, 0.f, 0.f, 0.f};

#define STAGE_TILE(KT, BUF)                                                     \
  {                                                                             \
    const ushort* kbase = Kb + (size_t)((KT) * 64) * RS;                        \
    const ushort* vbase = Vb + (size_t)((KT) * 64) * RS;                        \
    _Pragma("unroll")                                                           \
    for (int t = 0; t < 2; ++t) {                                               \
      int it = wave * 2 + t;                                                    \
      gload_lds16(kbase + (size_t)(it * 8 + kRow) * RS + kCol,                  \
                  &Ks[BUF][it * 512]);                                          \
      gload_lds16(vbase + (size_t)(it * 8 + vJ) * RS + vD,                      \
                  &Vs[BUF][it * 512]);                                          \
    }                                                                           \
  }

  STAGE_TILE(0, 0);
  __syncthreads();
  int cur = 0;
  const int pkey = (l16 & 7) << 3;
  ushort* Pw = Ps[wave];

  for (int kt = 0; kt < N_ / 64; ++kt) {
    if (kt + 1 < N_ / 64) STAGE_TILE(kt + 1, cur ^ 1);

    // ---- S^T = (K Q^T): lane holds q=l16, j = jt*16 + lq*4 + r ----
    f32x4 s[4];
    const ushort* Kc = Ks[cur];
#pragma unroll
    for (int jt = 0; jt < 4; ++jt) {
      int row = jt * 16 + l16, swz = l16 & 7;
      const ushort* kr = Kc + row * 64;
      bfx8 kv0 = *(const bfx8*)(kr + ((lq ^ swz) << 3));
      bfx8 kv1 = *(const bfx8*)(kr + (((lq + 4) ^ swz) << 3));
      f32x4 z = {0.f, 0.f, 0.f, 0.f};
      z = __builtin_amdgcn_mfma_f32_16x16x32_bf16(kv0, qf0, z, 0, 0, 0);
      z = __builtin_amdgcn_mfma_f32_16x16x32_bf16(kv1, qf1, z, 0, 0, 0);
      s[jt] = z;
    }

    // ---- lane-local max (tree) + cross-lq reduce (2 shfl) ----
    float t8[8];
#pragma unroll
    for (int i = 0; i < 8; ++i)
      t8[i] = fmaxf(s[i >> 1][(i & 1) * 2], s[i >> 1][(i & 1) * 2 + 1]);
    float t40 = fmaxf(t8[0], t8[1]), t41 = fmaxf(t8[2], t8[3]);
    float t42 = fmaxf(t8[4], t8[5]), t43 = fmaxf(t8[6], t8[7]);
    float tmax2 = fmaxf(fmaxf(t40, t41), fmaxf(t42, t43)) * CL;
    tmax2 = fmaxf(tmax2, __shfl_xor(tmax2, 16));
    tmax2 = fmaxf(tmax2, __shfl_xor(tmax2, 32));

    // ---- defer-max: rescale only when max grows past THR=8 (log2) ----
    if (!__all(tmax2 <= m2 + 8.0f)) {
      float mn2 = fmaxf(m2, tmax2);
      float darg = m2 - mn2, sc;
      asm("v_exp_f32 %0, %1" : "=v"(sc) : "v"(darg));
      m2 = mn2;
      l_s *= sc;
      float sco[4];
#pragma unroll
      for (int r = 0; r < 4; ++r) sco[r] = __shfl(sc, (lane & 48) + lq * 4 + r);
#pragma unroll
      for (int dt = 0; dt < 4; ++dt)
#pragma unroll
        for (int r = 0; r < 4; ++r) o[dt][r] *= sco[r];
    }

    // ---- P = 2^(s*CL - m2); pack pairs; 4x ds_write_b64 ----
    float tsum = 0.f;
#pragma unroll
    for (int jt = 0; jt < 4; ++jt) {
      float p[4];
#pragma unroll
      for (int r = 0; r < 4; ++r) {
        float a = __builtin_fmaf(s[jt][r], CL, -m2);
        asm("v_exp_f32 %0, %1" : "=v"(p[r]) : "v"(a));
      }
      tsum += (p[0] + p[1]) + (p[2] + p[3]);
      unsigned pk0, pk1;
      asm("v_cvt_pk_bf16_f32 %0, %1, %2" : "=v"(pk0) : "v"(p[0]), "v"(p[1]));
      asm("v_cvt_pk_bf16_f32 %0, %1, %2" : "=v"(pk1) : "v"(p[2]), "v"(p[3]));
      *(uint2*)(Pw + l16 * 64 + ((jt * 16 + lq * 4) ^ pkey)) = make_uint2(pk0, pk1);
    }
    l_s += tsum;

    // wave-private P: in-wave lgkm drain instead of a barrier
    asm volatile("s_waitcnt lgkmcnt(0)" ::: "memory");
    __builtin_amdgcn_sched_barrier(0);
    bfx8 pa0 = *(const bfx8*)(Pw + l16 * 64 + ((lq * 8) ^ pkey));
    bfx8 pa1 = *(const bfx8*)(Pw + l16 * 64 + ((32 + lq * 8) ^ pkey));

    // ---- PV: V via hardware transpose reads ----
    uint32_t vbase = lds_addr(&Vs[cur][0]) + (uint32_t)(lq * 1024 + l16 * 8);
#pragma unroll
    for (int kk = 0; kk < 2; ++kk) {
      bfx4 t[8];
#pragma unroll
      for (int dt = 0; dt < 4; ++dt)
#pragma unroll
        for (int hf = 0; hf < 2; ++hf) {
          uint32_t a = vbase + (uint32_t)(kk * 4096 + hf * 512 + dt * 128);
          asm volatile("ds_read_b64_tr_b16 %0, %1" : "=v"(t[dt * 2 + hf]) : "v"(a));
        }
      asm volatile("s_waitcnt lgkmcnt(0)" ::: "memory");
      __builtin_amdgcn_sched_barrier(0);
      bfx8 pa = kk ? pa1 : pa0;
#pragma unroll
      for (int dt = 0; dt < 4; ++dt) {
        bfx8 vf = __builtin_shufflevector(t[dt * 2], t[dt * 2 + 1],
                                          0, 1, 2, 3, 4, 5, 6, 7);
        o[dt] = __builtin_amdgcn_mfma_f32_16x16x32_bf16(pa, vf, o[dt], 0, 0, 0);
      }
    }
    __syncthreads();   // drains prefetch vmcnt + all waves done with buf[cur]
    cur ^= 1;
  }
#undef STAGE_TILE

  // ---- epilogue: reduce l across lq, redistribute, write attn (bf16) ----
  l_s += __shfl_xor(l_s, 16);
  l_s += __shfl_xor(l_s, 32);
  float inv = 1.0f / l_s;
  float linv[4];
#pragma unroll
  for (int r = 0; r < 4; ++r) linv[r] = __shfl(inv, (lane & 48) + lq * 4 + r);
#pragma unroll
  for (int dt = 0; dt < 4; ++dt)
#pragma unroll
    for (int r = 0; r < 4; ++r) {
      int n = q0 + wave * 16 + lq * 4 + r;
      int col = h * HS_ + dt * 16 + l16;
      outb[(size_t)(b * N_ + n) * C_ + col] = f2bf(o[dt][r] * linv[r]);
    }
}

// ---------------------------------------------------------------------------
extern "C" void kernel_launch(void* const* d_in, const int* in_sizes, int n_in,
                              void* d_out, int out_size, void* d_ws, size_t ws_size,
                              hipStream_t stream) {
  const float* x    = (const float*)d_in[0];
  const float* wqkv = (const float*)d_in[1];
  const float* wout = (const float*)d_in[2];
  const float* bout = (const float*)d_in[3];
  float* out = (float*)d_out;

  ushort* xb    = (ushort*)d_ws;
  ushort* wqkvb = xb + (size_t)M_TOT * C_;
  ushort* woutb = wqkvb + (size_t)QKV_N * C_;
  ushort* qkvb  = woutb + (size_t)C_ * C_;
  ushort* attnb = qkvb + (size_t)M_TOT * QKV_N;

  convert_kernel<<<2048, 256, 0, stream>>>((const float4*)x, (const float4*)wqkv,
                                           (const float4*)wout, xb, wqkvb, woutb);
  dim3 g1(QKV_N / 128, M_TOT / 128);
  gemm_bt<1><<<g1, 256, 0, stream>>>(xb, wqkvb, qkvb, nullptr, nullptr, M_TOT, QKV_N, C_);
  dim3 g2(N_ / 64, B_ * H_);
  attn_kernel<<<g2, 256, 0, stream>>>(qkvb, attnb);
  dim3 g3(C_ / 128, M_TOT / 128);
  gemm_bt<0><<<g3, 256, 0, stream>>>(attnb, woutb, nullptr, out, bout, M_TOT, C_, C_);
}

// Round 6
// 210.166 us; speedup vs baseline: 1.6027x; 1.0599x over previous
//
#include <hip/hip_runtime.h>
#include <hip/hip_bf16.h>

// MHSA: B=2, N=2048, C=1024, H=16, HS=64.
// Pipeline: convert(f32->bf16, permute w_qkv) -> QKV GEMM (256^2 8-phase bf16
// MFMA) -> flash attention (swapped QK^T, lane-local softmax) -> out GEMM.

typedef __attribute__((ext_vector_type(8))) short bfx8;
typedef __attribute__((ext_vector_type(4))) short bfx4;
typedef __attribute__((ext_vector_type(4))) float f32x4;

#define B_ 2
#define N_ 2048
#define C_ 1024
#define H_ 16
#define HS_ 64
#define M_TOT 4096     // B*N
#define QKV_N 3072     // 3*C

__device__ __forceinline__ ushort f2bf(float f) {
  union { float f; unsigned u; } v; v.f = f;
  unsigned r = v.u + 0x7FFFu + ((v.u >> 16) & 1u);  // RNE
  return (ushort)(r >> 16);
}

__device__ __forceinline__ void gload_lds16(const ushort* g, ushort* l) {
  __builtin_amdgcn_global_load_lds(
      (const __attribute__((address_space(1))) unsigned int*)g,
      (__attribute__((address_space(3))) unsigned int*)l, 16, 0, 0);
}

__device__ __forceinline__ uint32_t lds_addr(const ushort* p) {
  return (uint32_t)(size_t)(__attribute__((address_space(3))) const ushort*)p;
}

// ---------------------------------------------------------------------------
// f32 -> bf16 conversion. w_qkv rows permuted: j' = (j%3)*1024 + j/3 so the
// stride-3 q/k/v interleave becomes contiguous [Q | K | V] panels.
// ---------------------------------------------------------------------------
__global__ void convert_kernel(const float4* __restrict__ x,
                               const float4* __restrict__ wqkv,
                               const float4* __restrict__ wout,
                               ushort* __restrict__ xb,
                               ushort* __restrict__ wqkvb,
                               ushort* __restrict__ woutb) {
  const int NX = (M_TOT * C_) / 4;
  const int NW = (QKV_N * C_) / 4;
  const int NO = (C_ * C_) / 4;
  const int total = NX + NW + NO;
  const int stride = gridDim.x * blockDim.x;
  for (int i = blockIdx.x * blockDim.x + threadIdx.x; i < total; i += stride) {
    if (i < NX) {
      float4 v = x[i];
      ushort4 o; o.x = f2bf(v.x); o.y = f2bf(v.y); o.z = f2bf(v.z); o.w = f2bf(v.w);
      *(ushort4*)(xb + (size_t)i * 4) = o;
    } else if (i < NX + NW) {
      int q = i - NX;
      float4 v = wqkv[q];
      int e = q * 4;
      int j = e >> 10, col = e & 1023;
      int jp = ((j % 3) << 10) + (j / 3);
      ushort4 o; o.x = f2bf(v.x); o.y = f2bf(v.y); o.z = f2bf(v.z); o.w = f2bf(v.w);
      *(ushort4*)(wqkvb + ((size_t)jp << 10) + col) = o;
    } else {
      int q = i - NX - NW;
      float4 v = wout[q];
      ushort4 o; o.x = f2bf(v.x); o.y = f2bf(v.y); o.z = f2bf(v.z); o.w = f2bf(v.w);
      *(ushort4*)(woutb + (size_t)q * 4) = o;
    }
  }
}

// ---------------------------------------------------------------------------
// 256x256 tile, BK=64, 512 threads / 8 waves (2M x 4N), quadrant-phase
// schedule (T2 swizzle + T3/T4 prefetch-across-barriers + T5 setprio).
// C = A[M,K] * B[N,K]^T, bf16 out. LDS: 128 KiB dynamic, double-buffered.
// ---------------------------------------------------------------------------
__global__ __launch_bounds__(512, 2)
void gemm256(const ushort* __restrict__ A, const ushort* __restrict__ Bm,
             ushort* __restrict__ Cb, int M, int N, int K) {
  extern __shared__ ushort LDSU[];  // A[2][16384] | B[2][16384]
  const int tid = threadIdx.x;
  const int wave = tid >> 6, lane = tid & 63;
  const int l16 = lane & 15, lq = lane >> 4;
  const int wm = wave >> 2, wn = wave & 3;

  // bijective XCD swizzle (gridDim.x % 8 == 0)
  const int cpx = gridDim.x >> 3;
  const int tile = (blockIdx.x & 7) * cpx + (blockIdx.x >> 3);
  const int nbx = N >> 8;
  const int brow = (tile / nbx) << 8, bcol = (tile % nbx) << 8;

  // staging geometry: thread t covers row srow, swizzled col chunk
  const int srow = tid >> 3;                               // 0..63
  const int scol = ((tid * 8) & 63) ^ ((srow & 7) << 3);   // pre-swizzled src
  const ushort* Ab = A + (size_t)(brow + srow) * K + scol;
  const ushort* Bb = Bm + (size_t)(bcol + srow) * K + scol;
  const int sdst = tid * 8;

  f32x4 acc[8][4];
#pragma unroll
  for (int m = 0; m < 8; ++m)
#pragma unroll
    for (int n = 0; n < 4; ++n) acc[m][n] = f32x4{0.f, 0.f, 0.f, 0.f};

  const int key = (l16 & 7) << 3;
  const int aRowBase = wm * 128 + l16;    // + mf*16
  const int bRowBase = wn * 64 + l16;     // + nf*16

#define STAGE(KT, BUF)                                                        \
  {                                                                           \
    const ushort* a_ = Ab + (KT) * 64;                                        \
    const ushort* b_ = Bb + (KT) * 64;                                        \
    ushort* al_ = &LDSU[(BUF) * 16384 + sdst];                                \
    ushort* bl_ = &LDSU[32768 + (BUF) * 16384 + sdst];                        \
    _Pragma("unroll")                                                         \
    for (int i_ = 0; i_ < 4; ++i_) {                                          \
      gload_lds16(a_ + (size_t)(i_ * 64) * K, al_ + i_ * 4096);               \
      gload_lds16(b_ + (size_t)(i_ * 64) * K, bl_ + i_ * 4096);               \
    }                                                                         \
  }
#define RD_A(dst, mf, ks, BUF)                                                \
  dst = *(const bfx8*)&LDSU[(BUF) * 16384 + (aRowBase + (mf) * 16) * 64 +     \
                            ((((ks) * 32) + lq * 8) ^ key)];
#define RD_B(dst, nf, ks, BUF)                                                \
  dst = *(const bfx8*)&LDSU[32768 + (BUF) * 16384 +                           \
                            (bRowBase + (nf) * 16) * 64 +                     \
                            ((((ks) * 32) + lq * 8) ^ key)];

  STAGE(0, 0);
  asm volatile("s_waitcnt vmcnt(0)" ::: "memory");
  __syncthreads();

  const int NT = K >> 6;
  bfx8 af[8], b0[4], b1[4];
#pragma unroll 1
  for (int kt = 0; kt < NT; ++kt) {
    const int buf = kt & 1;
    // ---- phase q0: (mh0, nh0) ----
#pragma unroll
    for (int mf = 0; mf < 4; ++mf)
#pragma unroll
      for (int ks = 0; ks < 2; ++ks) RD_A(af[mf * 2 + ks], mf, ks, buf);
#pragma unroll
    for (int nf = 0; nf < 2; ++nf)
#pragma unroll
      for (int ks = 0; ks < 2; ++ks) RD_B(b0[nf * 2 + ks], nf, ks, buf);
    if (kt + 1 < NT) STAGE(kt + 1, buf ^ 1);
    __builtin_amdgcn_s_barrier();
    asm volatile("s_waitcnt lgkmcnt(0)" ::: "memory");
    __builtin_amdgcn_sched_barrier(0);
    __builtin_amdgcn_s_setprio(1);
#pragma unroll
    for (int mf = 0; mf < 4; ++mf)
#pragma unroll
      for (int nf = 0; nf < 2; ++nf)
#pragma unroll
        for (int ks = 0; ks < 2; ++ks)
          acc[mf][nf] = __builtin_amdgcn_mfma_f32_16x16x32_bf16(
              af[mf * 2 + ks], b0[nf * 2 + ks], acc[mf][nf], 0, 0, 0);
    __builtin_amdgcn_s_setprio(0);
    __builtin_amdgcn_s_barrier();
    // ---- phase q1: (mh0, nh1) ----
#pragma unroll
    for (int nf = 0; nf < 2; ++nf)
#pragma unroll
      for (int ks = 0; ks < 2; ++ks) RD_B(b1[nf * 2 + ks], nf + 2, ks, buf);
    __builtin_amdgcn_s_barrier();
    asm volatile("s_waitcnt lgkmcnt(0)" ::: "memory");
    __builtin_amdgcn_sched_barrier(0);
    __builtin_amdgcn_s_setprio(1);
#pragma unroll
    for (int mf = 0; mf < 4; ++mf)
#pragma unroll
      for (int nf = 0; nf < 2; ++nf)
#pragma unroll
        for (int ks = 0; ks < 2; ++ks)
          acc[mf][nf + 2] = __builtin_amdgcn_mfma_f32_16x16x32_bf16(
              af[mf * 2 + ks], b1[nf * 2 + ks], acc[mf][nf + 2], 0, 0, 0);
    __builtin_amdgcn_s_setprio(0);
    __builtin_amdgcn_s_barrier();
    // ---- phase q2: (mh1, nh1) ----
#pragma unroll
    for (int mf = 0; mf < 4; ++mf)
#pragma unroll
      for (int ks = 0; ks < 2; ++ks) RD_A(af[mf * 2 + ks], mf + 4, ks, buf);
    __builtin_amdgcn_s_barrier();
    asm volatile("s_waitcnt lgkmcnt(0)" ::: "memory");
    __builtin_amdgcn_sched_barrier(0);
    __builtin_amdgcn_s_setprio(1);
#pragma unroll
    for (int mf = 0; mf < 4; ++mf)
#pragma unroll
      for (int nf = 0; nf < 2; ++nf)
#pragma unroll
        for (int ks = 0; ks < 2; ++ks)
          acc[mf + 4][nf + 2] = __builtin_amdgcn_mfma_f32_16x16x32_bf16(
              af[mf * 2 + ks], b1[nf * 2 + ks], acc[mf + 4][nf + 2], 0, 0, 0);
    __builtin_amdgcn_s_setprio(0);
    __builtin_amdgcn_s_barrier();
    // ---- phase q3: (mh1, nh0) — no new reads (b0 retained) ----
    __builtin_amdgcn_s_setprio(1);
#pragma unroll
    for (int mf = 0; mf < 4; ++mf)
#pragma unroll
      for (int nf = 0; nf < 2; ++nf)
#pragma unroll
        for (int ks = 0; ks < 2; ++ks)
          acc[mf + 4][nf] = __builtin_amdgcn_mfma_f32_16x16x32_bf16(
              af[mf * 2 + ks], b0[nf * 2 + ks], acc[mf + 4][nf], 0, 0, 0);
    __builtin_amdgcn_s_setprio(0);
    asm volatile("s_waitcnt vmcnt(0)" ::: "memory");
    __builtin_amdgcn_s_barrier();   // publishes buf^1 for next K-tile
  }
#undef STAGE
#undef RD_A
#undef RD_B

#pragma unroll
  for (int mf = 0; mf < 8; ++mf)
#pragma unroll
    for (int nf = 0; nf < 4; ++nf)
#pragma unroll
      for (int r = 0; r < 4; ++r) {
        int grow = brow + wm * 128 + mf * 16 + lq * 4 + r;
        int gcol = bcol + wn * 64 + nf * 16 + l16;
        Cb[(size_t)grow * N + gcol] = f2bf(acc[mf][nf][r]);
      }
}

// ---------------------------------------------------------------------------
// GEMM: C[M,N] = A[M,K] * B[N,K]^T, 128x128 tile, BK=64, 4 waves (m97-style).
// Used for the output projection (f32 out + bias).
// ---------------------------------------------------------------------------
template<int STORE_BF16>
__global__ __launch_bounds__(256)
void gemm_bt(const ushort* __restrict__ A, const ushort* __restrict__ Bm,
             ushort* __restrict__ Cb, float* __restrict__ Cf,
             const float* __restrict__ bias, int M, int N, int K) {
  __shared__ ushort As[128 * 64];
  __shared__ ushort Bs[128 * 64];
  const int tid = threadIdx.x;
  const int wave = tid >> 6, lane = tid & 63;
  const int l16 = lane & 15, lq = lane >> 4;
  const int brow = blockIdx.y * 128, bcol = blockIdx.x * 128;
  const int wr = (wave >> 1) * 64, wc = (wave & 1) * 64;

  f32x4 acc[4][4];
#pragma unroll
  for (int m = 0; m < 4; ++m)
#pragma unroll
    for (int n = 0; n < 4; ++n) acc[m][n] = f32x4{0.f, 0.f, 0.f, 0.f};

  for (int k0 = 0; k0 < K; k0 += 64) {
    __syncthreads();
#pragma unroll
    for (int r = 0; r < 4; ++r) {
      int off = (r * 256 + tid) * 8;
      gload_lds16(A + (size_t)(brow + (off >> 6)) * K + k0 + (off & 63), As + off);
    }
#pragma unroll
    for (int r = 0; r < 4; ++r) {
      int off = (r * 256 + tid) * 8;
      gload_lds16(Bm + (size_t)(bcol + (off >> 6)) * K + k0 + (off & 63), Bs + off);
    }
    asm volatile("s_waitcnt vmcnt(0)" ::: "memory");
    __syncthreads();
#pragma unroll
    for (int kk = 0; kk < 64; kk += 32) {
      bfx8 a[4], b[4];
#pragma unroll
      for (int m = 0; m < 4; ++m)
        a[m] = *(const bfx8*)(As + (wr + m * 16 + l16) * 64 + kk + lq * 8);
#pragma unroll
      for (int n = 0; n < 4; ++n)
        b[n] = *(const bfx8*)(Bs + (wc + n * 16 + l16) * 64 + kk + lq * 8);
#pragma unroll
      for (int m = 0; m < 4; ++m)
#pragma unroll
        for (int n = 0; n < 4; ++n)
          acc[m][n] = __builtin_amdgcn_mfma_f32_16x16x32_bf16(a[m], b[n], acc[m][n], 0, 0, 0);
    }
  }
#pragma unroll
  for (int m = 0; m < 4; ++m)
#pragma unroll
    for (int n = 0; n < 4; ++n)
#pragma unroll
      for (int r = 0; r < 4; ++r) {
        int grow = brow + wr + m * 16 + lq * 4 + r;
        int gcol = bcol + wc + n * 16 + l16;
        if (STORE_BF16) {
          Cb[(size_t)grow * N + gcol] = f2bf(acc[m][n][r]);
        } else {
          Cf[(size_t)grow * N + gcol] = acc[m][n][r] + bias[gcol];
        }
      }
}

// ---------------------------------------------------------------------------
// Flash attention. Grid (N/64, B*H), 4 waves x 16 q-rows, KVBLK=64.
// S^T via mfma(K, Q): lane holds q=l16, j=jt*16+lq*4+r -> lane-local softmax
// (log2-domain exp, defer-max THR=8, per-lane partial l reduced at end).
// K LDS swizzled via pre-swizzled global source; V subtiled for tr_b16 reads.
// ---------------------------------------------------------------------------
__global__ __launch_bounds__(256)
void attn_kernel(const ushort* __restrict__ qkv, ushort* __restrict__ outb) {
  __shared__ ushort Ks[2][64 * 64];
  __shared__ ushort Vs[2][64 * 64];
  __shared__ ushort Ps[4][16 * 64];
  const int tid = threadIdx.x, wave = tid >> 6, lane = tid & 63;
  const int l16 = lane & 15, lq = lane >> 4;
  const int bh = blockIdx.y, b = bh >> 4, h = bh & 15;
  const int q0 = blockIdx.x * 64;
  const size_t RS = QKV_N;
  const ushort* Qb = qkv + ((size_t)(b * N_ + q0)) * RS + h * HS_;
  const ushort* Kb = qkv + ((size_t)(b * N_)) * RS + C_ + h * HS_;
  const ushort* Vb = qkv + ((size_t)(b * N_)) * RS + 2 * C_ + h * HS_;

  // per-lane staging geometry
  const int kRow = lane >> 3;                               // row within 8-row slab
  const int kCol = (((lane & 7) ^ (lane >> 3)) << 3);       // pre-swizzled k-slot
  const int vJ = ((lane >> 5) << 2) + ((lane & 7) >> 1);    // j within 8-row slab
  const int vD = ((lane >> 3) & 3) * 16 + (lane & 1) * 8;   // d offset

  bfx8 qf0, qf1;
  {
    const ushort* qrow = Qb + (size_t)(wave * 16 + l16) * RS + lq * 8;
    qf0 = *(const bfx8*)(qrow);
    qf1 = *(const bfx8*)(qrow + 32);
  }

  const float CL = 0.125f * 1.44269504f;   // SCALE * log2(e)
  float m2 = -1e30f, l_s = 0.f;            // per-lane stats for q = l16 (log2 dom)
  f32x4 o[4];
#pragma unroll
  for (int dt = 0; dt < 4; ++dt) o[dt] = f32x4{0.f, 0.f, 0.f, 0.f};

#define STAGE_TILE(KT, BUF)                                                     \
  {                                                                             \
    const ushort* kbase = Kb + (size_t)((KT) * 64) * RS;                        \
    const ushort* vbase = Vb + (size_t)((KT) * 64) * RS;                        \
    _Pragma("unroll")                                                           \
    for (int t = 0; t < 2; ++t) {                                               \
      int it = wave * 2 + t;                                                    \
      gload_lds16(kbase + (size_t)(it * 8 + kRow) * RS + kCol,                  \
                  &Ks[BUF][it * 512]);                                          \
      gload_lds16(vbase + (size_t)(it * 8 + vJ) * RS + vD,                      \
                  &Vs[BUF][it * 512]);                                          \
    }                                                                           \
  }

  STAGE_TILE(0, 0);
  __syncthreads();
  int cur = 0;
  const int pkey = (l16 & 7) << 3;
  ushort* Pw = Ps[wave];

  for (int kt = 0; kt < N_ / 64; ++kt) {
    if (kt + 1 < N_ / 64) STAGE_TILE(kt + 1, cur ^ 1);

    // ---- S^T = (K Q^T): lane holds q=l16, j = jt*16 + lq*4 + r ----
    f32x4 s[4];
    const ushort* Kc = Ks[cur];
#pragma unroll
    for (int jt = 0; jt < 4; ++jt) {
      int row = jt * 16 + l16, swz = l16 & 7;
      const ushort* kr = Kc + row * 64;
      bfx8 kv0 = *(const bfx8*)(kr + ((lq ^ swz) << 3));
      bfx8 kv1 = *(const bfx8*)(kr + (((lq + 4) ^ swz) << 3));
      f32x4 z = {0.f, 0.f, 0.f, 0.f};
      z = __builtin_amdgcn_mfma_f32_16x16x32_bf16(kv0, qf0, z, 0, 0, 0);
      z = __builtin_amdgcn_mfma_f32_16x16x32_bf16(kv1, qf1, z, 0, 0, 0);
      s[jt] = z;
    }

    // ---- lane-local max (tree) + cross-lq reduce (2 shfl) ----
    float t8[8];
#pragma unroll
    for (int i = 0; i < 8; ++i)
      t8[i] = fmaxf(s[i >> 1][(i & 1) * 2], s[i >> 1][(i & 1) * 2 + 1]);
    float t40 = fmaxf(t8[0], t8[1]), t41 = fmaxf(t8[2], t8[3]);
    float t42 = fmaxf(t8[4], t8[5]), t43 = fmaxf(t8[6], t8[7]);
    float tmax2 = fmaxf(fmaxf(t40, t41), fmaxf(t42, t43)) * CL;
    tmax2 = fmaxf(tmax2, __shfl_xor(tmax2, 16));
    tmax2 = fmaxf(tmax2, __shfl_xor(tmax2, 32));

    // ---- defer-max: rescale only when max grows past THR=8 (log2) ----
    if (!__all(tmax2 <= m2 + 8.0f)) {
      float mn2 = fmaxf(m2, tmax2);
      float darg = m2 - mn2, sc;
      asm("v_exp_f32 %0, %1" : "=v"(sc) : "v"(darg));
      m2 = mn2;
      l_s *= sc;
      float sco[4];
#pragma unroll
      for (int r = 0; r < 4; ++r) sco[r] = __shfl(sc, (lane & 48) + lq * 4 + r);
#pragma unroll
      for (int dt = 0; dt < 4; ++dt)
#pragma unroll
        for (int r = 0; r < 4; ++r) o[dt][r] *= sco[r];
    }

    // ---- P = 2^(s*CL - m2); pack pairs; 4x ds_write_b64 ----
    float tsum = 0.f;
#pragma unroll
    for (int jt = 0; jt < 4; ++jt) {
      float p[4];
#pragma unroll
      for (int r = 0; r < 4; ++r) {
        float a = __builtin_fmaf(s[jt][r], CL, -m2);
        asm("v_exp_f32 %0, %1" : "=v"(p[r]) : "v"(a));
      }
      tsum += (p[0] + p[1]) + (p[2] + p[3]);
      unsigned pk0, pk1;
      asm("v_cvt_pk_bf16_f32 %0, %1, %2" : "=v"(pk0) : "v"(p[0]), "v"(p[1]));
      asm("v_cvt_pk_bf16_f32 %0, %1, %2" : "=v"(pk1) : "v"(p[2]), "v"(p[3]));
      *(uint2*)(Pw + l16 * 64 + ((jt * 16 + lq * 4) ^ pkey)) = make_uint2(pk0, pk1);
    }
    l_s += tsum;

    // wave-private P: in-wave lgkm drain instead of a barrier
    asm volatile("s_waitcnt lgkmcnt(0)" ::: "memory");
    __builtin_amdgcn_sched_barrier(0);
    bfx8 pa0 = *(const bfx8*)(Pw + l16 * 64 + ((lq * 8) ^ pkey));
    bfx8 pa1 = *(const bfx8*)(Pw + l16 * 64 + ((32 + lq * 8) ^ pkey));

    // ---- PV: V via hardware transpose reads ----
    uint32_t vbase = lds_addr(&Vs[cur][0]) + (uint32_t)(lq * 1024 + l16 * 8);
#pragma unroll
    for (int kk = 0; kk < 2; ++kk) {
      bfx4 t[8];
#pragma unroll
      for (int dt = 0; dt < 4; ++dt)
#pragma unroll
        for (int hf = 0; hf < 2; ++hf) {
          uint32_t a = vbase + (uint32_t)(kk * 4096 + hf * 512 + dt * 128);
          asm volatile("ds_read_b64_tr_b16 %0, %1" : "=v"(t[dt * 2 + hf]) : "v"(a));
        }
      asm volatile("s_waitcnt lgkmcnt(0)" ::: "memory");
      __builtin_amdgcn_sched_barrier(0);
      bfx8 pa = kk ? pa1 : pa0;
#pragma unroll
      for (int dt = 0; dt < 4; ++dt) {
        bfx8 vf = __builtin_shufflevector(t[dt * 2], t[dt * 2 + 1],
                                          0, 1, 2, 3, 4, 5, 6, 7);
        o[dt] = __builtin_amdgcn_mfma_f32_16x16x32_bf16(pa, vf, o[dt], 0, 0, 0);
      }
    }
    __syncthreads();   // drains prefetch vmcnt + all waves done with buf[cur]
    cur ^= 1;
  }
#undef STAGE_TILE

  // ---- epilogue: reduce l across lq, redistribute, write attn (bf16) ----
  l_s += __shfl_xor(l_s, 16);
  l_s += __shfl_xor(l_s, 32);
  float inv = 1.0f / l_s;
  float linv[4];
#pragma unroll
  for (int r = 0; r < 4; ++r) linv[r] = __shfl(inv, (lane & 48) + lq * 4 + r);
#pragma unroll
  for (int dt = 0; dt < 4; ++dt)
#pragma unroll
    for (int r = 0; r < 4; ++r) {
      int n = q0 + wave * 16 + lq * 4 + r;
      int col = h * HS_ + dt * 16 + l16;
      outb[(size_t)(b * N_ + n) * C_ + col] = f2bf(o[dt][r] * linv[r]);
    }
}

// ---------------------------------------------------------------------------
extern "C" void kernel_launch(void* const* d_in, const int* in_sizes, int n_in,
                              void* d_out, int out_size, void* d_ws, size_t ws_size,
                              hipStream_t stream) {
  const float* x    = (const float*)d_in[0];
  const float* wqkv = (const float*)d_in[1];
  const float* wout = (const float*)d_in[2];
  const float* bout = (const float*)d_in[3];
  float* out = (float*)d_out;

  ushort* xb    = (ushort*)d_ws;
  ushort* wqkvb = xb + (size_t)M_TOT * C_;
  ushort* woutb = wqkvb + (size_t)QKV_N * C_;
  ushort* qkvb  = woutb + (size_t)C_ * C_;
  ushort* attnb = qkvb + (size_t)M_TOT * QKV_N;

  hipFuncSetAttribute((const void*)gemm256,
                      hipFuncAttributeMaxDynamicSharedMemorySize, 131072);

  convert_kernel<<<2048, 256, 0, stream>>>((const float4*)x, (const float4*)wqkv,
                                           (const float4*)wout, xb, wqkvb, woutb);
  // QKV GEMM: M=4096, N=3072 -> 16x12 = 192 blocks of 512 threads
  gemm256<<<192, 512, 131072, stream>>>(xb, wqkvb, qkvb, M_TOT, QKV_N, C_);
  dim3 g2(N_ / 64, B_ * H_);
  attn_kernel<<<g2, 256, 0, stream>>>(qkvb, attnb);
  dim3 g3(C_ / 128, M_TOT / 128);
  gemm_bt<0><<<g3, 256, 0, stream>>>(attnb, woutb, nullptr, out, bout, M_TOT, C_, C_);
}

// Round 7
// 207.255 us; speedup vs baseline: 1.6252x; 1.0140x over previous
//
#include <hip/hip_runtime.h>
#include <hip/hip_bf16.h>

// MHSA: B=2, N=2048, C=1024, H=16, HS=64.
// Pipeline: convert(f32->bf16, permute w_qkv) -> QKV GEMM (256^2 quadrant-
// phase bf16 MFMA) -> flash attention (swapped QK^T, lane-local softmax,
// x16-MFMA PV via k-permutation) -> out GEMM.

typedef __attribute__((ext_vector_type(8))) short bfx8;
typedef __attribute__((ext_vector_type(4))) short bfx4;
typedef __attribute__((ext_vector_type(4))) float f32x4;

#define B_ 2
#define N_ 2048
#define C_ 1024
#define H_ 16
#define HS_ 64
#define M_TOT 4096     // B*N
#define QKV_N 3072     // 3*C

__device__ __forceinline__ ushort f2bf(float f) {
  union { float f; unsigned u; } v; v.f = f;
  unsigned r = v.u + 0x7FFFu + ((v.u >> 16) & 1u);  // RNE
  return (ushort)(r >> 16);
}

__device__ __forceinline__ void gload_lds16(const ushort* g, ushort* l) {
  __builtin_amdgcn_global_load_lds(
      (const __attribute__((address_space(1))) unsigned int*)g,
      (__attribute__((address_space(3))) unsigned int*)l, 16, 0, 0);
}

__device__ __forceinline__ uint32_t lds_addr(const ushort* p) {
  return (uint32_t)(size_t)(__attribute__((address_space(3))) const ushort*)p;
}

// ---------------------------------------------------------------------------
// f32 -> bf16 conversion. w_qkv rows permuted: j' = (j%3)*1024 + j/3 so the
// stride-3 q/k/v interleave becomes contiguous [Q | K | V] panels.
// ---------------------------------------------------------------------------
__global__ void convert_kernel(const float4* __restrict__ x,
                               const float4* __restrict__ wqkv,
                               const float4* __restrict__ wout,
                               ushort* __restrict__ xb,
                               ushort* __restrict__ wqkvb,
                               ushort* __restrict__ woutb) {
  const int NX = (M_TOT * C_) / 4;
  const int NW = (QKV_N * C_) / 4;
  const int NO = (C_ * C_) / 4;
  const int total = NX + NW + NO;
  const int stride = gridDim.x * blockDim.x;
  for (int i = blockIdx.x * blockDim.x + threadIdx.x; i < total; i += stride) {
    if (i < NX) {
      float4 v = x[i];
      ushort4 o; o.x = f2bf(v.x); o.y = f2bf(v.y); o.z = f2bf(v.z); o.w = f2bf(v.w);
      *(ushort4*)(xb + (size_t)i * 4) = o;
    } else if (i < NX + NW) {
      int q = i - NX;
      float4 v = wqkv[q];
      int e = q * 4;
      int j = e >> 10, col = e & 1023;
      int jp = ((j % 3) << 10) + (j / 3);
      ushort4 o; o.x = f2bf(v.x); o.y = f2bf(v.y); o.z = f2bf(v.z); o.w = f2bf(v.w);
      *(ushort4*)(wqkvb + ((size_t)jp << 10) + col) = o;
    } else {
      int q = i - NX - NW;
      float4 v = wout[q];
      ushort4 o; o.x = f2bf(v.x); o.y = f2bf(v.y); o.z = f2bf(v.z); o.w = f2bf(v.w);
      *(ushort4*)(woutb + (size_t)q * 4) = o;
    }
  }
}

// ---------------------------------------------------------------------------
// 256x256 tile, BK=64, 512 threads / 8 waves (2M x 4N), quadrant-phase
// schedule (T2 swizzle + T3/T4 prefetch-across-barriers + T5 setprio).
// C = A[M,K] * B[N,K]^T, bf16 out. LDS: 128 KiB dynamic, double-buffered.
// ---------------------------------------------------------------------------
__global__ __launch_bounds__(512, 2)
void gemm256(const ushort* __restrict__ A, const ushort* __restrict__ Bm,
             ushort* __restrict__ Cb, int M, int N, int K) {
  extern __shared__ ushort LDSU[];  // A[2][16384] | B[2][16384]
  const int tid = threadIdx.x;
  const int wave = tid >> 6, lane = tid & 63;
  const int l16 = lane & 15, lq = lane >> 4;
  const int wm = wave >> 2, wn = wave & 3;

  // bijective XCD swizzle (gridDim.x % 8 == 0)
  const int cpx = gridDim.x >> 3;
  const int tile = (blockIdx.x & 7) * cpx + (blockIdx.x >> 3);
  const int nbx = N >> 8;
  const int brow = (tile / nbx) << 8, bcol = (tile % nbx) << 8;

  // staging geometry: thread t covers row srow, swizzled col chunk
  const int srow = tid >> 3;                               // 0..63
  const int scol = ((tid * 8) & 63) ^ ((srow & 7) << 3);   // pre-swizzled src
  const ushort* Ab = A + (size_t)(brow + srow) * K + scol;
  const ushort* Bb = Bm + (size_t)(bcol + srow) * K + scol;
  const int sdst = tid * 8;

  f32x4 acc[8][4];
#pragma unroll
  for (int m = 0; m < 8; ++m)
#pragma unroll
    for (int n = 0; n < 4; ++n) acc[m][n] = f32x4{0.f, 0.f, 0.f, 0.f};

  const int key = (l16 & 7) << 3;
  const int aRowBase = wm * 128 + l16;    // + mf*16
  const int bRowBase = wn * 64 + l16;     // + nf*16

#define STAGE(KT, BUF)                                                        \
  {                                                                           \
    const ushort* a_ = Ab + (KT) * 64;                                        \
    const ushort* b_ = Bb + (KT) * 64;                                        \
    ushort* al_ = &LDSU[(BUF) * 16384 + sdst];                                \
    ushort* bl_ = &LDSU[32768 + (BUF) * 16384 + sdst];                        \
    _Pragma("unroll")                                                         \
    for (int i_ = 0; i_ < 4; ++i_) {                                          \
      gload_lds16(a_ + (size_t)(i_ * 64) * K, al_ + i_ * 4096);               \
      gload_lds16(b_ + (size_t)(i_ * 64) * K, bl_ + i_ * 4096);               \
    }                                                                         \
  }
#define RD_A(dst, mf, ks, BUF)                                                \
  dst = *(const bfx8*)&LDSU[(BUF) * 16384 + (aRowBase + (mf) * 16) * 64 +     \
                            ((((ks) * 32) + lq * 8) ^ key)];
#define RD_B(dst, nf, ks, BUF)                                                \
  dst = *(const bfx8*)&LDSU[32768 + (BUF) * 16384 +                           \
                            (bRowBase + (nf) * 16) * 64 +                     \
                            ((((ks) * 32) + lq * 8) ^ key)];

  STAGE(0, 0);
  asm volatile("s_waitcnt vmcnt(0)" ::: "memory");
  __syncthreads();

  const int NT = K >> 6;
  bfx8 af[8], b0[4], b1[4];
#pragma unroll 1
  for (int kt = 0; kt < NT; ++kt) {
    const int buf = kt & 1;
    // ---- phase q0: (mh0, nh0) ----
#pragma unroll
    for (int mf = 0; mf < 4; ++mf)
#pragma unroll
      for (int ks = 0; ks < 2; ++ks) RD_A(af[mf * 2 + ks], mf, ks, buf);
#pragma unroll
    for (int nf = 0; nf < 2; ++nf)
#pragma unroll
      for (int ks = 0; ks < 2; ++ks) RD_B(b0[nf * 2 + ks], nf, ks, buf);
    if (kt + 1 < NT) STAGE(kt + 1, buf ^ 1);
    __builtin_amdgcn_s_barrier();
    asm volatile("s_waitcnt lgkmcnt(0)" ::: "memory");
    __builtin_amdgcn_sched_barrier(0);
    __builtin_amdgcn_s_setprio(1);
#pragma unroll
    for (int mf = 0; mf < 4; ++mf)
#pragma unroll
      for (int nf = 0; nf < 2; ++nf)
#pragma unroll
        for (int ks = 0; ks < 2; ++ks)
          acc[mf][nf] = __builtin_amdgcn_mfma_f32_16x16x32_bf16(
              af[mf * 2 + ks], b0[nf * 2 + ks], acc[mf][nf], 0, 0, 0);
    __builtin_amdgcn_s_setprio(0);
    __builtin_amdgcn_s_barrier();
    // ---- phase q1: (mh0, nh1) ----
#pragma unroll
    for (int nf = 0; nf < 2; ++nf)
#pragma unroll
      for (int ks = 0; ks < 2; ++ks) RD_B(b1[nf * 2 + ks], nf + 2, ks, buf);
    __builtin_amdgcn_s_barrier();
    asm volatile("s_waitcnt lgkmcnt(0)" ::: "memory");
    __builtin_amdgcn_sched_barrier(0);
    __builtin_amdgcn_s_setprio(1);
#pragma unroll
    for (int mf = 0; mf < 4; ++mf)
#pragma unroll
      for (int nf = 0; nf < 2; ++nf)
#pragma unroll
        for (int ks = 0; ks < 2; ++ks)
          acc[mf][nf + 2] = __builtin_amdgcn_mfma_f32_16x16x32_bf16(
              af[mf * 2 + ks], b1[nf * 2 + ks], acc[mf][nf + 2], 0, 0, 0);
    __builtin_amdgcn_s_setprio(0);
    __builtin_amdgcn_s_barrier();
    // ---- phase q2: (mh1, nh1) ----
#pragma unroll
    for (int mf = 0; mf < 4; ++mf)
#pragma unroll
      for (int ks = 0; ks < 2; ++ks) RD_A(af[mf * 2 + ks], mf + 4, ks, buf);
    __builtin_amdgcn_s_barrier();
    asm volatile("s_waitcnt lgkmcnt(0)" ::: "memory");
    __builtin_amdgcn_sched_barrier(0);
    __builtin_amdgcn_s_setprio(1);
#pragma unroll
    for (int mf = 0; mf < 4; ++mf)
#pragma unroll
      for (int nf = 0; nf < 2; ++nf)
#pragma unroll
        for (int ks = 0; ks < 2; ++ks)
          acc[mf + 4][nf + 2] = __builtin_amdgcn_mfma_f32_16x16x32_bf16(
              af[mf * 2 + ks], b1[nf * 2 + ks], acc[mf + 4][nf + 2], 0, 0, 0);
    __builtin_amdgcn_s_setprio(0);
    __builtin_amdgcn_s_barrier();
    // ---- phase q3: (mh1, nh0) — no new reads (b0 retained) ----
    __builtin_amdgcn_s_setprio(1);
#pragma unroll
    for (int mf = 0; mf < 4; ++mf)
#pragma unroll
      for (int nf = 0; nf < 2; ++nf)
#pragma unroll
        for (int ks = 0; ks < 2; ++ks)
          acc[mf + 4][nf] = __builtin_amdgcn_mfma_f32_16x16x32_bf16(
              af[mf * 2 + ks], b0[nf * 2 + ks], acc[mf + 4][nf], 0, 0, 0);
    __builtin_amdgcn_s_setprio(0);
    asm volatile("s_waitcnt vmcnt(0)" ::: "memory");
    __builtin_amdgcn_s_barrier();   // publishes buf^1 for next K-tile
  }
#undef STAGE
#undef RD_A
#undef RD_B

#pragma unroll
  for (int mf = 0; mf < 8; ++mf)
#pragma unroll
    for (int nf = 0; nf < 4; ++nf)
#pragma unroll
      for (int r = 0; r < 4; ++r) {
        int grow = brow + wm * 128 + mf * 16 + lq * 4 + r;
        int gcol = bcol + wn * 64 + nf * 16 + l16;
        Cb[(size_t)grow * N + gcol] = f2bf(acc[mf][nf][r]);
      }
}

// ---------------------------------------------------------------------------
// GEMM: C[M,N] = A[M,K] * B[N,K]^T, 128x128 tile, BK=64, 4 waves (m97-style).
// Used for the output projection (f32 out + bias).
// ---------------------------------------------------------------------------
template<int STORE_BF16>
__global__ __launch_bounds__(256)
void gemm_bt(const ushort* __restrict__ A, const ushort* __restrict__ Bm,
             ushort* __restrict__ Cb, float* __restrict__ Cf,
             const float* __restrict__ bias, int M, int N, int K) {
  __shared__ ushort As[128 * 64];
  __shared__ ushort Bs[128 * 64];
  const int tid = threadIdx.x;
  const int wave = tid >> 6, lane = tid & 63;
  const int l16 = lane & 15, lq = lane >> 4;
  const int brow = blockIdx.y * 128, bcol = blockIdx.x * 128;
  const int wr = (wave >> 1) * 64, wc = (wave & 1) * 64;

  f32x4 acc[4][4];
#pragma unroll
  for (int m = 0; m < 4; ++m)
#pragma unroll
    for (int n = 0; n < 4; ++n) acc[m][n] = f32x4{0.f, 0.f, 0.f, 0.f};

  for (int k0 = 0; k0 < K; k0 += 64) {
    __syncthreads();
#pragma unroll
    for (int r = 0; r < 4; ++r) {
      int off = (r * 256 + tid) * 8;
      gload_lds16(A + (size_t)(brow + (off >> 6)) * K + k0 + (off & 63), As + off);
    }
#pragma unroll
    for (int r = 0; r < 4; ++r) {
      int off = (r * 256 + tid) * 8;
      gload_lds16(Bm + (size_t)(bcol + (off >> 6)) * K + k0 + (off & 63), Bs + off);
    }
    asm volatile("s_waitcnt vmcnt(0)" ::: "memory");
    __syncthreads();
#pragma unroll
    for (int kk = 0; kk < 64; kk += 32) {
      bfx8 a[4], b[4];
#pragma unroll
      for (int m = 0; m < 4; ++m)
        a[m] = *(const bfx8*)(As + (wr + m * 16 + l16) * 64 + kk + lq * 8);
#pragma unroll
      for (int n = 0; n < 4; ++n)
        b[n] = *(const bfx8*)(Bs + (wc + n * 16 + l16) * 64 + kk + lq * 8);
#pragma unroll
      for (int m = 0; m < 4; ++m)
#pragma unroll
        for (int n = 0; n < 4; ++n)
          acc[m][n] = __builtin_amdgcn_mfma_f32_16x16x32_bf16(a[m], b[n], acc[m][n], 0, 0, 0);
    }
  }
#pragma unroll
  for (int m = 0; m < 4; ++m)
#pragma unroll
    for (int n = 0; n < 4; ++n)
#pragma unroll
      for (int r = 0; r < 4; ++r) {
        int grow = brow + wr + m * 16 + lq * 4 + r;
        int gcol = bcol + wc + n * 16 + l16;
        if (STORE_BF16) {
          Cb[(size_t)grow * N + gcol] = f2bf(acc[m][n][r]);
        } else {
          Cf[(size_t)grow * N + gcol] = acc[m][n][r] + bias[gcol];
        }
      }
}

// ---------------------------------------------------------------------------
// Flash attention. Grid (N/64, B*H), 4 waves x 16 q-rows, KVBLK=64.
// S^T via mfma(K, Q): lane holds q=l16, j=jt*16+lq*4+r -> lane-local softmax.
// PV via 16x16x16 MFMA with a consistent k-slot permutation
// (j = kk*32 + lq*8 + hf*4 + e on BOTH operands): each ds_read_b64_tr_b16
// result is directly a B-frag; the A-frag is one ds_read_b64 from swizzled P.
// ---------------------------------------------------------------------------
__global__ __launch_bounds__(256)
void attn_kernel(const ushort* __restrict__ qkv, ushort* __restrict__ outb) {
  __shared__ ushort Ks[2][64 * 64];
  __shared__ ushort Vs[2][64 * 64];
  __shared__ ushort Ps[4][16 * 64];
  const int tid = threadIdx.x, wave = tid >> 6, lane = tid & 63;
  const int l16 = lane & 15, lq = lane >> 4;
  const int bh = blockIdx.y, b = bh >> 4, h = bh & 15;
  const int q0 = blockIdx.x * 64;
  const size_t RS = QKV_N;
  const ushort* Qb = qkv + ((size_t)(b * N_ + q0)) * RS + h * HS_;
  const ushort* Kb = qkv + ((size_t)(b * N_)) * RS + C_ + h * HS_;
  const ushort* Vb = qkv + ((size_t)(b * N_)) * RS + 2 * C_ + h * HS_;

  // per-lane staging geometry
  const int kRow = lane >> 3;                               // row within 8-row slab
  const int kCol = (((lane & 7) ^ (lane >> 3)) << 3);       // pre-swizzled k-slot
  const int vJ = ((lane >> 5) << 2) + ((lane & 7) >> 1);    // j within 8-row slab
  const int vD = ((lane >> 3) & 3) * 16 + (lane & 1) * 8;   // d offset

  bfx8 qf0, qf1;
  {
    const ushort* qrow = Qb + (size_t)(wave * 16 + l16) * RS + lq * 8;
    qf0 = *(const bfx8*)(qrow);
    qf1 = *(const bfx8*)(qrow + 32);
  }

  const float CL = 0.125f * 1.44269504f;   // SCALE * log2(e)
  float m2 = -1e30f, l_s = 0.f;            // per-lane stats for q = l16 (log2 dom)
  f32x4 o[4];
#pragma unroll
  for (int dt = 0; dt < 4; ++dt) o[dt] = f32x4{0.f, 0.f, 0.f, 0.f};

#define STAGE_TILE(KT, BUF)                                                     \
  {                                                                             \
    const ushort* kbase = Kb + (size_t)((KT) * 64) * RS;                        \
    const ushort* vbase_ = Vb + (size_t)((KT) * 64) * RS;                       \
    _Pragma("unroll")                                                           \
    for (int t = 0; t < 2; ++t) {                                               \
      int it = wave * 2 + t;                                                    \
      gload_lds16(kbase + (size_t)(it * 8 + kRow) * RS + kCol,                  \
                  &Ks[BUF][it * 512]);                                          \
      gload_lds16(vbase_ + (size_t)(it * 8 + vJ) * RS + vD,                     \
                  &Vs[BUF][it * 512]);                                          \
    }                                                                           \
  }

  STAGE_TILE(0, 0);
  __syncthreads();
  int cur = 0;
  const int pkey = (l16 & 7) << 3;
  ushort* Pw = Ps[wave];

  for (int kt = 0; kt < N_ / 64; ++kt) {
    if (kt + 1 < N_ / 64) STAGE_TILE(kt + 1, cur ^ 1);

    // ---- S^T = (K Q^T): lane holds q=l16, j = jt*16 + lq*4 + r ----
    f32x4 s[4];
    const ushort* Kc = Ks[cur];
#pragma unroll
    for (int jt = 0; jt < 4; ++jt) {
      int row = jt * 16 + l16, swz = l16 & 7;
      const ushort* kr = Kc + row * 64;
      bfx8 kv0 = *(const bfx8*)(kr + ((lq ^ swz) << 3));
      bfx8 kv1 = *(const bfx8*)(kr + (((lq + 4) ^ swz) << 3));
      f32x4 z = {0.f, 0.f, 0.f, 0.f};
      z = __builtin_amdgcn_mfma_f32_16x16x32_bf16(kv0, qf0, z, 0, 0, 0);
      z = __builtin_amdgcn_mfma_f32_16x16x32_bf16(kv1, qf1, z, 0, 0, 0);
      s[jt] = z;
    }

    // ---- lane-local max (max3-friendly tree) + cross-lq reduce (2 shfl) ----
    float x0 = fmaxf(fmaxf(s[0][0], s[0][1]), s[0][2]);
    float x1 = fmaxf(fmaxf(s[0][3], s[1][0]), s[1][1]);
    float x2 = fmaxf(fmaxf(s[1][2], s[1][3]), s[2][0]);
    float x3 = fmaxf(fmaxf(s[2][1], s[2][2]), s[2][3]);
    float x4 = fmaxf(fmaxf(s[3][0], s[3][1]), s[3][2]);
    float tmax2 = fmaxf(fmaxf(fmaxf(x0, x1), x2),
                        fmaxf(fmaxf(x3, x4), s[3][3])) * CL;
    tmax2 = fmaxf(tmax2, __shfl_xor(tmax2, 16));
    tmax2 = fmaxf(tmax2, __shfl_xor(tmax2, 32));

    // ---- defer-max: rescale only when max grows past THR=8 (log2) ----
    if (!__all(tmax2 <= m2 + 8.0f)) {
      float mn2 = fmaxf(m2, tmax2);
      float darg = m2 - mn2, sc;
      asm("v_exp_f32 %0, %1" : "=v"(sc) : "v"(darg));
      m2 = mn2;
      l_s *= sc;
      float sco[4];
#pragma unroll
      for (int r = 0; r < 4; ++r) sco[r] = __shfl(sc, (lane & 48) + lq * 4 + r);
#pragma unroll
      for (int dt = 0; dt < 4; ++dt)
#pragma unroll
        for (int r = 0; r < 4; ++r) o[dt][r] *= sco[r];
    }

    // ---- P = 2^(s*CL - m2); pack pairs; 4x ds_write_b64 ----
    float tsum = 0.f;
#pragma unroll
    for (int jt = 0; jt < 4; ++jt) {
      float p[4];
#pragma unroll
      for (int r = 0; r < 4; ++r) {
        float a = __builtin_fmaf(s[jt][r], CL, -m2);
        asm("v_exp_f32 %0, %1" : "=v"(p[r]) : "v"(a));
      }
      tsum += (p[0] + p[1]) + (p[2] + p[3]);
      unsigned pk0, pk1;
      asm("v_cvt_pk_bf16_f32 %0, %1, %2" : "=v"(pk0) : "v"(p[0]), "v"(p[1]));
      asm("v_cvt_pk_bf16_f32 %0, %1, %2" : "=v"(pk1) : "v"(p[2]), "v"(p[3]));
      *(uint2*)(Pw + l16 * 64 + ((jt * 16 + lq * 4) ^ pkey)) = make_uint2(pk0, pk1);
    }
    l_s += tsum;

    // ---- drain P writes (wave-private), then issue ALL PV LDS reads ----
    asm volatile("s_waitcnt lgkmcnt(0)" ::: "memory");
    __builtin_amdgcn_sched_barrier(0);
    // A-frags: P[q=l16][j = kk*32 + lq*8 + hf*4 + e], e=0..3 (one b64 each)
    bfx4 pa[4];
#pragma unroll
    for (int kk = 0; kk < 2; ++kk)
#pragma unroll
      for (int hf = 0; hf < 2; ++hf)
        pa[kk * 2 + hf] = *(const bfx4*)(Pw + l16 * 64 +
                                         (((kk * 32 + lq * 8) ^ pkey) + hf * 4));
    // B-frags: tr_b16 reads, offset immediates (kk*4096 + hf*512 + dt*128)
    uint32_t vbase = lds_addr(&Vs[cur][0]) + (uint32_t)(lq * 1024 + l16 * 8);
    bfx4 tv[16];   // tv[dt*4 + kk*2 + hf]
#define TRRD(i, off) \
    asm volatile("ds_read_b64_tr_b16 %0, %1 offset:" #off : "=v"(tv[i]) : "v"(vbase))
    TRRD(0, 0);    TRRD(1, 512);  TRRD(2, 4096);  TRRD(3, 4608);
    TRRD(4, 128);  TRRD(5, 640);  TRRD(6, 4224);  TRRD(7, 4736);
    TRRD(8, 256);  TRRD(9, 768);  TRRD(10, 4352); TRRD(11, 4864);
    TRRD(12, 384); TRRD(13, 896); TRRD(14, 4480); TRRD(15, 4992);
#undef TRRD
    asm volatile("s_waitcnt lgkmcnt(0)" ::: "memory");
    __builtin_amdgcn_sched_barrier(0);
    // ---- PV: 16x mfma_f32_16x16x16_bf16 (k-permutation consistent) ----
#pragma unroll
    for (int dt = 0; dt < 4; ++dt)
#pragma unroll
      for (int f = 0; f < 4; ++f)
        asm("v_mfma_f32_16x16x16_bf16 %0, %1, %2, %0"
            : "+v"(o[dt]) : "v"(pa[f]), "v"(tv[dt * 4 + f]));
    __syncthreads();   // drains prefetch vmcnt + all waves done with buf[cur]
    cur ^= 1;
  }
#undef STAGE_TILE

  // ---- epilogue: reduce l across lq, redistribute, write attn (bf16) ----
  l_s += __shfl_xor(l_s, 16);
  l_s += __shfl_xor(l_s, 32);
  float inv = 1.0f / l_s;
  float linv[4];
#pragma unroll
  for (int r = 0; r < 4; ++r) linv[r] = __shfl(inv, (lane & 48) + lq * 4 + r);
#pragma unroll
  for (int dt = 0; dt < 4; ++dt)
#pragma unroll
    for (int r = 0; r < 4; ++r) {
      int n = q0 + wave * 16 + lq * 4 + r;
      int col = h * HS_ + dt * 16 + l16;
      outb[(size_t)(b * N_ + n) * C_ + col] = f2bf(o[dt][r] * linv[r]);
    }
}

// ---------------------------------------------------------------------------
extern "C" void kernel_launch(void* const* d_in, const int* in_sizes, int n_in,
                              void* d_out, int out_size, void* d_ws, size_t ws_size,
                              hipStream_t stream) {
  const float* x    = (const float*)d_in[0];
  const float* wqkv = (const float*)d_in[1];
  const float* wout = (const float*)d_in[2];
  const float* bout = (const float*)d_in[3];
  float* out = (float*)d_out;

  ushort* xb    = (ushort*)d_ws;
  ushort* wqkvb = xb + (size_t)M_TOT * C_;
  ushort* woutb = wqkvb + (size_t)QKV_N * C_;
  ushort* qkvb  = woutb + (size_t)C_ * C_;
  ushort* attnb = qkvb + (size_t)M_TOT * QKV_N;

  hipFuncSetAttribute((const void*)gemm256,
                      hipFuncAttributeMaxDynamicSharedMemorySize, 131072);

  convert_kernel<<<2048, 256, 0, stream>>>((const float4*)x, (const float4*)wqkv,
                                           (const float4*)wout, xb, wqkvb, woutb);
  // QKV GEMM: M=4096, N=3072 -> 16x12 = 192 blocks of 512 threads
  gemm256<<<192, 512, 131072, stream>>>(xb, wqkvb, qkvb, M_TOT, QKV_N, C_);
  dim3 g2(N_ / 64, B_ * H_);
  attn_kernel<<<g2, 256, 0, stream>>>(qkvb, attnb);
  dim3 g3(C_ / 128, M_TOT / 128);
  gemm_bt<0><<<g3, 256, 0, stream>>>(attnb, woutb, nullptr, out, bout, M_TOT, C_, C_);
}

// Round 10
// 205.183 us; speedup vs baseline: 1.6416x; 1.0101x over previous
//
#include <hip/hip_runtime.h>
#include <hip/hip_bf16.h>

// MHSA: B=2, N=2048, C=1024, H=16, HS=64.
// Pipeline: convert(f32->bf16, permute w_qkv) -> QKV GEMM (256^2 quadrant-
// phase bf16 MFMA) -> flash attention (swapped QK^T, lane-local softmax,
// x16-MFMA PV, XCD-clustered bh) -> out GEMM (XCD-clustered row panels).

typedef __attribute__((ext_vector_type(8))) short bfx8;
typedef __attribute__((ext_vector_type(4))) short bfx4;
typedef __attribute__((ext_vector_type(4))) float f32x4;

#define B_ 2
#define N_ 2048
#define C_ 1024
#define H_ 16
#define HS_ 64
#define M_TOT 4096     // B*N
#define QKV_N 3072     // 3*C

__device__ __forceinline__ ushort f2bf(float f) {
  union { float f; unsigned u; } v; v.f = f;
  unsigned r = v.u + 0x7FFFu + ((v.u >> 16) & 1u);  // RNE
  return (ushort)(r >> 16);
}

__device__ __forceinline__ void gload_lds16(const ushort* g, ushort* l) {
  __builtin_amdgcn_global_load_lds(
      (const __attribute__((address_space(1))) unsigned int*)g,
      (__attribute__((address_space(3))) unsigned int*)l, 16, 0, 0);
}

__device__ __forceinline__ uint32_t lds_addr(const ushort* p) {
  return (uint32_t)(size_t)(__attribute__((address_space(3))) const ushort*)p;
}

// ---------------------------------------------------------------------------
// f32 -> bf16 conversion. w_qkv rows permuted: j' = (j%3)*1024 + j/3 so the
// stride-3 q/k/v interleave becomes contiguous [Q | K | V] panels.
// ---------------------------------------------------------------------------
__global__ void convert_kernel(const float4* __restrict__ x,
                               const float4* __restrict__ wqkv,
                               const float4* __restrict__ wout,
                               ushort* __restrict__ xb,
                               ushort* __restrict__ wqkvb,
                               ushort* __restrict__ woutb) {
  const int NX = (M_TOT * C_) / 4;
  const int NW = (QKV_N * C_) / 4;
  const int NO = (C_ * C_) / 4;
  const int total = NX + NW + NO;
  const int stride = gridDim.x * blockDim.x;
  for (int i = blockIdx.x * blockDim.x + threadIdx.x; i < total; i += stride) {
    if (i < NX) {
      float4 v = x[i];
      ushort4 o; o.x = f2bf(v.x); o.y = f2bf(v.y); o.z = f2bf(v.z); o.w = f2bf(v.w);
      *(ushort4*)(xb + (size_t)i * 4) = o;
    } else if (i < NX + NW) {
      int q = i - NX;
      float4 v = wqkv[q];
      int e = q * 4;
      int j = e >> 10, col = e & 1023;
      int jp = ((j % 3) << 10) + (j / 3);
      ushort4 o; o.x = f2bf(v.x); o.y = f2bf(v.y); o.z = f2bf(v.z); o.w = f2bf(v.w);
      *(ushort4*)(wqkvb + ((size_t)jp << 10) + col) = o;
    } else {
      int q = i - NX - NW;
      float4 v = wout[q];
      ushort4 o; o.x = f2bf(v.x); o.y = f2bf(v.y); o.z = f2bf(v.z); o.w = f2bf(v.w);
      *(ushort4*)(woutb + (size_t)q * 4) = o;
    }
  }
}

// ---------------------------------------------------------------------------
// 256x256 tile, BK=64, 512 threads / 8 waves (2M x 4N), quadrant-phase
// schedule (T2 swizzle + T3/T4 prefetch-across-barriers + T5 setprio).
// C = A[M,K] * B[N,K]^T, bf16 out. LDS: 128 KiB dynamic, double-buffered.
// ---------------------------------------------------------------------------
__global__ __launch_bounds__(512, 2)
void gemm256(const ushort* __restrict__ A, const ushort* __restrict__ Bm,
             ushort* __restrict__ Cb, int M, int N, int K) {
  extern __shared__ ushort LDSU[];  // A[2][16384] | B[2][16384]
  const int tid = threadIdx.x;
  const int wave = tid >> 6, lane = tid & 63;
  const int l16 = lane & 15, lq = lane >> 4;
  const int wm = wave >> 2, wn = wave & 3;

  // bijective XCD swizzle (gridDim.x % 8 == 0)
  const int cpx = gridDim.x >> 3;
  const int tile = (blockIdx.x & 7) * cpx + (blockIdx.x >> 3);
  const int nbx = N >> 8;
  const int brow = (tile / nbx) << 8, bcol = (tile % nbx) << 8;

  // staging geometry: thread t covers row srow, swizzled col chunk
  const int srow = tid >> 3;                               // 0..63
  const int scol = ((tid * 8) & 63) ^ ((srow & 7) << 3);   // pre-swizzled src
  const ushort* Ab = A + (size_t)(brow + srow) * K + scol;
  const ushort* Bb = Bm + (size_t)(bcol + srow) * K + scol;
  const int sdst = tid * 8;

  f32x4 acc[8][4];
#pragma unroll
  for (int m = 0; m < 8; ++m)
#pragma unroll
    for (int n = 0; n < 4; ++n) acc[m][n] = f32x4{0.f, 0.f, 0.f, 0.f};

  const int key = (l16 & 7) << 3;
  const int aRowBase = wm * 128 + l16;    // + mf*16
  const int bRowBase = wn * 64 + l16;     // + nf*16

#define STAGE(KT, BUF)                                                        \
  {                                                                           \
    const ushort* a_ = Ab + (KT) * 64;                                        \
    const ushort* b_ = Bb + (KT) * 64;                                        \
    ushort* al_ = &LDSU[(BUF) * 16384 + sdst];                                \
    ushort* bl_ = &LDSU[32768 + (BUF) * 16384 + sdst];                        \
    _Pragma("unroll")                                                         \
    for (int i_ = 0; i_ < 4; ++i_) {                                          \
      gload_lds16(a_ + (size_t)(i_ * 64) * K, al_ + i_ * 4096);               \
      gload_lds16(b_ + (size_t)(i_ * 64) * K, bl_ + i_ * 4096);               \
    }                                                                         \
  }
#define RD_A(dst, mf, ks, BUF)                                                \
  dst = *(const bfx8*)&LDSU[(BUF) * 16384 + (aRowBase + (mf) * 16) * 64 +     \
                            ((((ks) * 32) + lq * 8) ^ key)];
#define RD_B(dst, nf, ks, BUF)                                                \
  dst = *(const bfx8*)&LDSU[32768 + (BUF) * 16384 +                           \
                            (bRowBase + (nf) * 16) * 64 +                     \
                            ((((ks) * 32) + lq * 8) ^ key)];

  STAGE(0, 0);
  asm volatile("s_waitcnt vmcnt(0)" ::: "memory");
  __syncthreads();

  const int NT = K >> 6;
  bfx8 af[8], b0[4], b1[4];
#pragma unroll 1
  for (int kt = 0; kt < NT; ++kt) {
    const int buf = kt & 1;
    // ---- phase q0: (mh0, nh0) ----
#pragma unroll
    for (int mf = 0; mf < 4; ++mf)
#pragma unroll
      for (int ks = 0; ks < 2; ++ks) RD_A(af[mf * 2 + ks], mf, ks, buf);
#pragma unroll
    for (int nf = 0; nf < 2; ++nf)
#pragma unroll
      for (int ks = 0; ks < 2; ++ks) RD_B(b0[nf * 2 + ks], nf, ks, buf);
    if (kt + 1 < NT) STAGE(kt + 1, buf ^ 1);
    __builtin_amdgcn_s_barrier();
    asm volatile("s_waitcnt lgkmcnt(0)" ::: "memory");
    __builtin_amdgcn_sched_barrier(0);
    __builtin_amdgcn_s_setprio(1);
#pragma unroll
    for (int mf = 0; mf < 4; ++mf)
#pragma unroll
      for (int nf = 0; nf < 2; ++nf)
#pragma unroll
        for (int ks = 0; ks < 2; ++ks)
          acc[mf][nf] = __builtin_amdgcn_mfma_f32_16x16x32_bf16(
              af[mf * 2 + ks], b0[nf * 2 + ks], acc[mf][nf], 0, 0, 0);
    __builtin_amdgcn_s_setprio(0);
    __builtin_amdgcn_s_barrier();
    // ---- phase q1: (mh0, nh1) ----
#pragma unroll
    for (int nf = 0; nf < 2; ++nf)
#pragma unroll
      for (int ks = 0; ks < 2; ++ks) RD_B(b1[nf * 2 + ks], nf + 2, ks, buf);
    __builtin_amdgcn_s_barrier();
    asm volatile("s_waitcnt lgkmcnt(0)" ::: "memory");
    __builtin_amdgcn_sched_barrier(0);
    __builtin_amdgcn_s_setprio(1);
#pragma unroll
    for (int mf = 0; mf < 4; ++mf)
#pragma unroll
      for (int nf = 0; nf < 2; ++nf)
#pragma unroll
        for (int ks = 0; ks < 2; ++ks)
          acc[mf][nf + 2] = __builtin_amdgcn_mfma_f32_16x16x32_bf16(
              af[mf * 2 + ks], b1[nf * 2 + ks], acc[mf][nf + 2], 0, 0, 0);
    __builtin_amdgcn_s_setprio(0);
    __builtin_amdgcn_s_barrier();
    // ---- phase q2: (mh1, nh1) ----
#pragma unroll
    for (int mf = 0; mf < 4; ++mf)
#pragma unroll
      for (int ks = 0; ks < 2; ++ks) RD_A(af[mf * 2 + ks], mf + 4, ks, buf);
    __builtin_amdgcn_s_barrier();
    asm volatile("s_waitcnt lgkmcnt(0)" ::: "memory");
    __builtin_amdgcn_sched_barrier(0);
    __builtin_amdgcn_s_setprio(1);
#pragma unroll
    for (int mf = 0; mf < 4; ++mf)
#pragma unroll
      for (int nf = 0; nf < 2; ++nf)
#pragma unroll
        for (int ks = 0; ks < 2; ++ks)
          acc[mf + 4][nf + 2] = __builtin_amdgcn_mfma_f32_16x16x32_bf16(
              af[mf * 2 + ks], b1[nf * 2 + ks], acc[mf + 4][nf + 2], 0, 0, 0);
    __builtin_amdgcn_s_setprio(0);
    __builtin_amdgcn_s_barrier();
    // ---- phase q3: (mh1, nh0) — no new reads (b0 retained) ----
    __builtin_amdgcn_s_setprio(1);
#pragma unroll
    for (int mf = 0; mf < 4; ++mf)
#pragma unroll
      for (int nf = 0; nf < 2; ++nf)
#pragma unroll
        for (int ks = 0; ks < 2; ++ks)
          acc[mf + 4][nf] = __builtin_amdgcn_mfma_f32_16x16x32_bf16(
              af[mf * 2 + ks], b0[nf * 2 + ks], acc[mf + 4][nf], 0, 0, 0);
    __builtin_amdgcn_s_setprio(0);
    asm volatile("s_waitcnt vmcnt(0)" ::: "memory");
    __builtin_amdgcn_s_barrier();   // publishes buf^1 for next K-tile
  }
#undef STAGE
#undef RD_A
#undef RD_B

#pragma unroll
  for (int mf = 0; mf < 8; ++mf)
#pragma unroll
    for (int nf = 0; nf < 4; ++nf)
#pragma unroll
      for (int r = 0; r < 4; ++r) {
        int grow = brow + wm * 128 + mf * 16 + lq * 4 + r;
        int gcol = bcol + wn * 64 + nf * 16 + l16;
        Cb[(size_t)grow * N + gcol] = f2bf(acc[mf][nf][r]);
      }
}

// ---------------------------------------------------------------------------
// GEMM: C[M,N] = A[M,K] * B[N,K]^T, 128x128 tile, BK=64, 4 waves (m97-style).
// Flat grid + chunked XCD swizzle: the N/128 col-blocks sharing an A-row
// panel land on one XCD (panel L2-resident). f32 out + bias.
// ---------------------------------------------------------------------------
template<int STORE_BF16>
__global__ __launch_bounds__(256)
void gemm_bt(const ushort* __restrict__ A, const ushort* __restrict__ Bm,
             ushort* __restrict__ Cb, float* __restrict__ Cf,
             const float* __restrict__ bias, int M, int N, int K) {
  __shared__ ushort As[128 * 64];
  __shared__ ushort Bs[128 * 64];
  const int tid = threadIdx.x;
  const int wave = tid >> 6, lane = tid & 63;
  const int l16 = lane & 15, lq = lane >> 4;
  // bijective chunked XCD swizzle (gridDim.x % 8 == 0)
  const int cpx = gridDim.x >> 3;
  const int wg = (blockIdx.x & 7) * cpx + (blockIdx.x >> 3);
  const int nbx = N >> 7;
  const int brow = (wg / nbx) << 7, bcol = (wg % nbx) << 7;
  const int wr = (wave >> 1) * 64, wc = (wave & 1) * 64;

  f32x4 acc[4][4];
#pragma unroll
  for (int m = 0; m < 4; ++m)
#pragma unroll
    for (int n = 0; n < 4; ++n) acc[m][n] = f32x4{0.f, 0.f, 0.f, 0.f};

  for (int k0 = 0; k0 < K; k0 += 64) {
    __syncthreads();
#pragma unroll
    for (int r = 0; r < 4; ++r) {
      int off = (r * 256 + tid) * 8;
      gload_lds16(A + (size_t)(brow + (off >> 6)) * K + k0 + (off & 63), As + off);
    }
#pragma unroll
    for (int r = 0; r < 4; ++r) {
      int off = (r * 256 + tid) * 8;
      gload_lds16(Bm + (size_t)(bcol + (off >> 6)) * K + k0 + (off & 63), Bs + off);
    }
    asm volatile("s_waitcnt vmcnt(0)" ::: "memory");
    __syncthreads();
#pragma unroll
    for (int kk = 0; kk < 64; kk += 32) {
      bfx8 a[4], b[4];
#pragma unroll
      for (int m = 0; m < 4; ++m)
        a[m] = *(const bfx8*)(As + (wr + m * 16 + l16) * 64 + kk + lq * 8);
#pragma unroll
      for (int n = 0; n < 4; ++n)
        b[n] = *(const bfx8*)(Bs + (wc + n * 16 + l16) * 64 + kk + lq * 8);
#pragma unroll
      for (int m = 0; m < 4; ++m)
#pragma unroll
        for (int n = 0; n < 4; ++n)
          acc[m][n] = __builtin_amdgcn_mfma_f32_16x16x32_bf16(a[m], b[n], acc[m][n], 0, 0, 0);
    }
  }
#pragma unroll
  for (int m = 0; m < 4; ++m)
#pragma unroll
    for (int n = 0; n < 4; ++n)
#pragma unroll
      for (int r = 0; r < 4; ++r) {
        int grow = brow + wr + m * 16 + lq * 4 + r;
        int gcol = bcol + wc + n * 16 + l16;
        if (STORE_BF16) {
          Cb[(size_t)grow * N + gcol] = f2bf(acc[m][n][r]);
        } else {
          Cf[(size_t)grow * N + gcol] = acc[m][n][r] + bias[gcol];
        }
      }
}

// ---------------------------------------------------------------------------
// Flash attention. Flat grid 1024, chunked XCD swizzle clusters each head's
// 32 q-tiles on one XCD (K/V panels L2-resident). 4 waves x 16 q-rows,
// KVBLK=64. S^T via mfma(K, Q): lane holds q=l16, j=jt*16+lq*4+r ->
// lane-local softmax (log2 exp, defer-max THR=8). PV via 16x16x16 MFMA with
// consistent k-slot permutation; P round-trips through swizzled LDS.
// ---------------------------------------------------------------------------
__global__ __launch_bounds__(256)
void attn_kernel(const ushort* __restrict__ qkv, ushort* __restrict__ outb) {
  __shared__ ushort Ks[2][64 * 64];
  __shared__ ushort Vs[2][64 * 64];
  __shared__ ushort Ps[4][16 * 64];
  const int tid = threadIdx.x, wave = tid >> 6, lane = tid & 63;
  const int l16 = lane & 15, lq = lane >> 4;
  // bijective chunked XCD swizzle: wg in [0,1024), bh-major (qt fastest)
  const int cpx = gridDim.x >> 3;   // 128
  const int wg = (blockIdx.x & 7) * cpx + (blockIdx.x >> 3);
  const int bh = wg >> 5, b = bh >> 4, h = bh & 15;
  const int q0 = (wg & 31) * 64;
  const size_t RS = QKV_N;
  const ushort* Qb = qkv + ((size_t)(b * N_ + q0)) * RS + h * HS_;
  const ushort* Kb = qkv + ((size_t)(b * N_)) * RS + C_ + h * HS_;
  const ushort* Vb = qkv + ((size_t)(b * N_)) * RS + 2 * C_ + h * HS_;

  // per-lane staging geometry
  const int kRow = lane >> 3;                               // row within 8-row slab
  const int kCol = (((lane & 7) ^ (lane >> 3)) << 3);       // pre-swizzled k-slot
  const int vJ = ((lane >> 5) << 2) + ((lane & 7) >> 1);    // j within 8-row slab
  const int vD = ((lane >> 3) & 3) * 16 + (lane & 1) * 8;   // d offset

  bfx8 qf0, qf1;
  {
    const ushort* qrow = Qb + (size_t)(wave * 16 + l16) * RS + lq * 8;
    qf0 = *(const bfx8*)(qrow);
    qf1 = *(const bfx8*)(qrow + 32);
  }

  const float CL = 0.125f * 1.44269504f;   // SCALE * log2(e)
  float m2 = -1e30f, l_s = 0.f;            // per-lane stats for q = l16 (log2 dom)
  f32x4 o[4];
#pragma unroll
  for (int dt = 0; dt < 4; ++dt) o[dt] = f32x4{0.f, 0.f, 0.f, 0.f};

#define STAGE_TILE(KT, BUF)                                                     \
  {                                                                             \
    const ushort* kbase = Kb + (size_t)((KT) * 64) * RS;                        \
    const ushort* vbase_ = Vb + (size_t)((KT) * 64) * RS;                       \
    _Pragma("unroll")                                                           \
    for (int t = 0; t < 2; ++t) {                                               \
      int it = wave * 2 + t;                                                    \
      gload_lds16(kbase + (size_t)(it * 8 + kRow) * RS + kCol,                  \
                  &Ks[BUF][it * 512]);                                          \
      gload_lds16(vbase_ + (size_t)(it * 8 + vJ) * RS + vD,                     \
                  &Vs[BUF][it * 512]);                                          \
    }                                                                           \
  }

  STAGE_TILE(0, 0);
  __syncthreads();
  int cur = 0;
  const int pkey = (l16 & 7) << 3;
  ushort* Pw = Ps[wave];

  for (int kt = 0; kt < N_ / 64; ++kt) {
    if (kt + 1 < N_ / 64) STAGE_TILE(kt + 1, cur ^ 1);

    // ---- S^T = (K Q^T): lane holds q=l16, j = jt*16 + lq*4 + r ----
    f32x4 s[4];
    const ushort* Kc = Ks[cur];
#pragma unroll
    for (int jt = 0; jt < 4; ++jt) {
      int row = jt * 16 + l16, swz = l16 & 7;
      const ushort* kr = Kc + row * 64;
      bfx8 kv0 = *(const bfx8*)(kr + ((lq ^ swz) << 3));
      bfx8 kv1 = *(const bfx8*)(kr + (((lq + 4) ^ swz) << 3));
      f32x4 z = {0.f, 0.f, 0.f, 0.f};
      z = __builtin_amdgcn_mfma_f32_16x16x32_bf16(kv0, qf0, z, 0, 0, 0);
      z = __builtin_amdgcn_mfma_f32_16x16x32_bf16(kv1, qf1, z, 0, 0, 0);
      s[jt] = z;
    }

    // ---- lane-local max (max3-friendly tree) + cross-lq reduce (2 shfl) ----
    float x0 = fmaxf(fmaxf(s[0][0], s[0][1]), s[0][2]);
    float x1 = fmaxf(fmaxf(s[0][3], s[1][0]), s[1][1]);
    float x2 = fmaxf(fmaxf(s[1][2], s[1][3]), s[2][0]);
    float x3 = fmaxf(fmaxf(s[2][1], s[2][2]), s[2][3]);
    float x4 = fmaxf(fmaxf(s[3][0], s[3][1]), s[3][2]);
    float tmax2 = fmaxf(fmaxf(fmaxf(x0, x1), x2),
                        fmaxf(fmaxf(x3, x4), s[3][3])) * CL;
    tmax2 = fmaxf(tmax2, __shfl_xor(tmax2, 16));
    tmax2 = fmaxf(tmax2, __shfl_xor(tmax2, 32));

    // ---- defer-max: rescale only when max grows past THR=8 (log2) ----
    if (!__all(tmax2 <= m2 + 8.0f)) {
      float mn2 = fmaxf(m2, tmax2);
      float darg = m2 - mn2, sc;
      asm("v_exp_f32 %0, %1" : "=v"(sc) : "v"(darg));
      m2 = mn2;
      l_s *= sc;
      float sco[4];
#pragma unroll
      for (int r = 0; r < 4; ++r) sco[r] = __shfl(sc, (lane & 48) + lq * 4 + r);
#pragma unroll
      for (int dt = 0; dt < 4; ++dt)
#pragma unroll
        for (int r = 0; r < 4; ++r) o[dt][r] *= sco[r];
    }

    // ---- P = 2^(s*CL - m2); pack pairs; 4x ds_write_b64 ----
    float tsum = 0.f;
#pragma unroll
    for (int jt = 0; jt < 4; ++jt) {
      float p[4];
#pragma unroll
      for (int r = 0; r < 4; ++r) {
        float a = __builtin_fmaf(s[jt][r], CL, -m2);
        asm("v_exp_f32 %0, %1" : "=v"(p[r]) : "v"(a));
      }
      tsum += (p[0] + p[1]) + (p[2] + p[3]);
      unsigned pk0, pk1;
      asm("v_cvt_pk_bf16_f32 %0, %1, %2" : "=v"(pk0) : "v"(p[0]), "v"(p[1]));
      asm("v_cvt_pk_bf16_f32 %0, %1, %2" : "=v"(pk1) : "v"(p[2]), "v"(p[3]));
      *(uint2*)(Pw + l16 * 64 + ((jt * 16 + lq * 4) ^ pkey)) = make_uint2(pk0, pk1);
    }
    l_s += tsum;

    // ---- drain P writes (wave-private), then issue ALL PV LDS reads ----
    asm volatile("s_waitcnt lgkmcnt(0)" ::: "memory");
    __builtin_amdgcn_sched_barrier(0);
    // A-frags: P[q=l16][j = kk*32 + lq*8 + hf*4 + e], e=0..3 (one b64 each)
    bfx4 pa[4];
#pragma unroll
    for (int kk = 0; kk < 2; ++kk)
#pragma unroll
      for (int hf = 0; hf < 2; ++hf)
        pa[kk * 2 + hf] = *(const bfx4*)(Pw + l16 * 64 +
                                         (((kk * 32 + lq * 8) ^ pkey) + hf * 4));
    // B-frags: tr_b16 reads, offset immediates (kk*4096 + hf*512 + dt*128)
    uint32_t vbase = lds_addr(&Vs[cur][0]) + (uint32_t)(lq * 1024 + l16 * 8);
    bfx4 tv[16];   // tv[dt*4 + kk*2 + hf]
#define TRRD(i, off) \
    asm volatile("ds_read_b64_tr_b16 %0, %1 offset:" #off : "=v"(tv[i]) : "v"(vbase))
    TRRD(0, 0);    TRRD(1, 512);  TRRD(2, 4096);  TRRD(3, 4608);
    TRRD(4, 128);  TRRD(5, 640);  TRRD(6, 4224);  TRRD(7, 4736);
    TRRD(8, 256);  TRRD(9, 768);  TRRD(10, 4352); TRRD(11, 4864);
    TRRD(12, 384); TRRD(13, 896); TRRD(14, 4480); TRRD(15, 4992);
#undef TRRD
    asm volatile("s_waitcnt lgkmcnt(0)" ::: "memory");
    __builtin_amdgcn_sched_barrier(0);
    // ---- PV: 16x mfma_f32_16x16x16_bf16 (k-permutation consistent) ----
#pragma unroll
    for (int dt = 0; dt < 4; ++dt)
#pragma unroll
      for (int f = 0; f < 4; ++f)
        asm("v_mfma_f32_16x16x16_bf16 %0, %1, %2, %0"
            : "+v"(o[dt]) : "v"(pa[f]), "v"(tv[dt * 4 + f]));
    __syncthreads();   // drains prefetch vmcnt + all waves done with buf[cur]
    cur ^= 1;
  }
#undef STAGE_TILE

  // ---- epilogue: reduce l across lq, redistribute, write attn (bf16) ----
  l_s += __shfl_xor(l_s, 16);
  l_s += __shfl_xor(l_s, 32);
  float inv = 1.0f / l_s;
  float linv[4];
#pragma unroll
  for (int r = 0; r < 4; ++r) linv[r] = __shfl(inv, (lane & 48) + lq * 4 + r);
#pragma unroll
  for (int dt = 0; dt < 4; ++dt)
#pragma unroll
    for (int r = 0; r < 4; ++r) {
      int n = q0 + wave * 16 + lq * 4 + r;
      int col = h * HS_ + dt * 16 + l16;
      outb[(size_t)(b * N_ + n) * C_ + col] = f2bf(o[dt][r] * linv[r]);
    }
}

// ---------------------------------------------------------------------------
extern "C" void kernel_launch(void* const* d_in, const int* in_sizes, int n_in,
                              void* d_out, int out_size, void* d_ws, size_t ws_size,
                              hipStream_t stream) {
  const float* x    = (const float*)d_in[0];
  const float* wqkv = (const float*)d_in[1];
  const float* wout = (const float*)d_in[2];
  const float* bout = (const float*)d_in[3];
  float* out = (float*)d_out;

  ushort* xb    = (ushort*)d_ws;
  ushort* wqkvb = xb + (size_t)M_TOT * C_;
  ushort* woutb = wqkvb + (size_t)QKV_N * C_;
  ushort* qkvb  = woutb + (size_t)C_ * C_;
  ushort* attnb = qkvb + (size_t)M_TOT * QKV_N;

  hipFuncSetAttribute((const void*)gemm256,
                      hipFuncAttributeMaxDynamicSharedMemorySize, 131072);

  convert_kernel<<<2048, 256, 0, stream>>>((const float4*)x, (const float4*)wqkv,
                                           (const float4*)wout, xb, wqkvb, woutb);
  // QKV GEMM: M=4096, N=3072 -> 16x12 = 192 blocks of 512 threads
  gemm256<<<192, 512, 131072, stream>>>(xb, wqkvb, qkvb, M_TOT, QKV_N, C_);
  // attention: flat 1024 blocks (32 bh x 32 q-tiles), XCD-clustered by bh
  attn_kernel<<<1024, 256, 0, stream>>>(qkvb, attnb);
  // out projection: flat 256 blocks (32 row-panels x 8 col-blocks)
  gemm_bt<0><<<256, 256, 0, stream>>>(attnb, woutb, nullptr, out, bout,
                                      M_TOT, C_, C_);
}